// Round 1
// baseline (3489.806 us; speedup 1.0000x reference)
//
#include <hip/hip_runtime.h>

// ============================================================
// CustomUltrasoundViT: 12-layer ViT (B=4, S=1025->pad 1088=17*64, D=768, H=12,
// HD=64, MLP=3072) + cross-attn + 3 heads. bf16 MFMA GEMMs, fp32 residual.
// R3: register-staged + LDS double-buffered GEMM K-loop (one barrier/iter,
// prefetch loads stay in flight across barriers); 128x64 tiles for N=768.
// R4: (a) pad 1152->1088 (-5.6% FLOPs everywhere); (b) operand-swapped MFMA
// (C^T fragments) so each thread's 4 acc regs = 4 consecutive n of one row ->
// vectorized epilogues (8B bf16 stores, float4 RMW for residual) instead of
// 64 scalar 2B stores / 128 scalar fp32 RMW per thread; (c) logits_k as
// wave-per-row shuffle reduction (was 33-65 blocks, latency-bound).
// ============================================================

#define SP 1088   // padded sequence length (17*64)

typedef __attribute__((ext_vector_type(8))) short short8;
typedef __attribute__((ext_vector_type(4))) short s16x4;
typedef __attribute__((ext_vector_type(4))) float floatx4;

#define EPI_BF16  0
#define EPI_BIAS  1
#define EPI_QKV   2
#define EPI_RES   3
#define EPI_GELU  4
#define EPI_PATCH 5

__device__ __forceinline__ short f2bf(float f) {
    union { float f; unsigned u; } x; x.f = f;
    return (short)((x.u + 0x7fffu + ((x.u >> 16) & 1u)) >> 16);
}
__device__ __forceinline__ float bf2f(short s) {
    union { unsigned u; float f; } x; x.u = ((unsigned)(unsigned short)s) << 16;
    return x.f;
}
__device__ __forceinline__ float gelu_f(float x) {
    return 0.5f * x * (1.f + erff(x * 0.70710678118654752f));
}
__device__ __forceinline__ void gload_lds16(const void* g, void* l) {
    __builtin_amdgcn_global_load_lds((const __attribute__((address_space(1))) void*)g,
                                     (__attribute__((address_space(3))) void*)l, 16, 0, 0);
}

// ------------------------------------------------------------
// gemm_bt: C[M,N] = A[M,K] @ BT[N,K]^T (row-major bf16-as-short).
// BM=128. BN=128: 4 waves 2x2 (64x64 each). BN=64: 4 waves 2x2 (64x32 each).
// K-loop: global->VGPR prefetch (2 tiles deep, survives barriers) ->
// ds_write -> single barrier -> ds_read frags -> MFMA. LDS double-buffered.
// MFMA operands SWAPPED (computes C^T fragments): reg index r maps to
// consecutive n, so epilogue stores are 8B/16B vectors.
// ------------------------------------------------------------
template<int BN, int EPI>
__global__ __launch_bounds__(256)
void gemm_bt(const short* __restrict__ A, int lda,
             const short* __restrict__ Bt, int ldb, int K,
             short* __restrict__ O, int ldo,
             const float* __restrict__ bias0, const float* __restrict__ bias1,
             const float* __restrict__ bias2, float* __restrict__ hres,
             const float* __restrict__ pos,
             short* __restrict__ kout, short* __restrict__ vout)
{
    constexpr int BCH = BN / 64;                 // B-tile 16B chunks per thread
    constexpr int WNS = (BN == 128) ? 64 : 32;   // wave N span
    constexpr int NJ  = WNS / 16;
    __shared__ __align__(16) short As[2][128 * 32];
    __shared__ __align__(16) short Bs[2][BN * 32];

    const int tid = threadIdx.x;
    const int m0 = blockIdx.x * 128, n0 = blockIdx.y * BN;
    const int wave = tid >> 6, lane = tid & 63;
    const int quad = lane >> 4, l15 = lane & 15;
    const int wm = wave >> 1, wn = wave & 1;
    const int srow = tid >> 2, scol = (tid & 3) * 8;

    const short* Ag = A + (long)(m0 + srow) * lda + scol;
    const short* Bg = Bt + (long)(n0 + srow) * ldb + scol;

    const int NIT = K >> 5;                      // always even, >= 12
    short8 ra[2][2], rb[2][BCH];
    #pragma unroll
    for (int pp = 0; pp < 2; pp++) {
        #pragma unroll
        for (int c = 0; c < 2; c++)
            ra[pp][c] = *(const short8*)(Ag + (long)(64 * c) * lda + pp * 32);
        #pragma unroll
        for (int c = 0; c < BCH; c++)
            rb[pp][c] = *(const short8*)(Bg + (long)(64 * c) * ldb + pp * 32);
    }

    floatx4 acc[4][NJ];
    #pragma unroll
    for (int i = 0; i < 4; i++)
        #pragma unroll
        for (int j = 0; j < NJ; j++)
            acc[i][j] = floatx4{0.f, 0.f, 0.f, 0.f};

    auto step = [&](int it, int pp) {
        short* as = As[pp];
        short* bs = Bs[pp];
        // regs -> LDS (tile it)
        #pragma unroll
        for (int c = 0; c < 2; c++)
            *(short8*)&as[(srow + 64 * c) * 32 + scol] = ra[pp][c];
        #pragma unroll
        for (int c = 0; c < BCH; c++)
            *(short8*)&bs[(srow + 64 * c) * 32 + scol] = rb[pp][c];
        __syncthreads();
        // issue global loads for tile it+2 (private regs: not drained by barriers)
        if (it + 2 < NIT) {
            const int k0 = (it + 2) * 32;
            #pragma unroll
            for (int c = 0; c < 2; c++)
                ra[pp][c] = *(const short8*)(Ag + (long)(64 * c) * lda + k0);
            #pragma unroll
            for (int c = 0; c < BCH; c++)
                rb[pp][c] = *(const short8*)(Bg + (long)(64 * c) * ldb + k0);
        }
        // LDS -> frags -> MFMA (swapped operands: acc holds C^T fragments)
        short8 af[4], bfrag[NJ];
        #pragma unroll
        for (int i = 0; i < 4; i++)
            af[i] = *(const short8*)&as[(wm * 64 + i * 16 + l15) * 32 + quad * 8];
        #pragma unroll
        for (int j = 0; j < NJ; j++)
            bfrag[j] = *(const short8*)&bs[(wn * WNS + j * 16 + l15) * 32 + quad * 8];
        #pragma unroll
        for (int i = 0; i < 4; i++)
            #pragma unroll
            for (int j = 0; j < NJ; j++)
                acc[i][j] = __builtin_amdgcn_mfma_f32_16x16x32_bf16(bfrag[j], af[i], acc[i][j], 0, 0, 0);
        // no trailing barrier: next iter writes the other LDS buffer
    };

    #pragma unroll 1
    for (int it = 0; it < NIT; it += 2) {
        step(it, 0);
        step(it + 1, 1);
    }

    // epilogue: thread (quad,l15) holds C[m = .. + l15][n = .. + quad*4 + r]
    const int mb = m0 + wm * 64 + l15;
    const int nbase = n0 + wn * WNS + quad * 4;
    #pragma unroll
    for (int i = 0; i < 4; i++) {
        const int m = mb + i * 16;
        #pragma unroll
        for (int j = 0; j < NJ; j++) {
            const int n = nbase + j * 16;
            floatx4 c4 = acc[i][j];
            if constexpr (EPI == EPI_BF16) {
                s16x4 s;
                #pragma unroll
                for (int r = 0; r < 4; r++) s[r] = f2bf(c4[r]);
                *(s16x4*)(O + (long)m * ldo + n) = s;
            } else if constexpr (EPI == EPI_BIAS) {
                floatx4 bv = *(const floatx4*)(bias0 + n);
                s16x4 s;
                #pragma unroll
                for (int r = 0; r < 4; r++) s[r] = f2bf(c4[r] + bv[r]);
                *(s16x4*)(O + (long)m * ldo + n) = s;
            } else if constexpr (EPI == EPI_QKV) {
                if (n < 768) {
                    floatx4 bv = *(const floatx4*)(bias0 + n);
                    s16x4 s;
                    #pragma unroll
                    for (int r = 0; r < 4; r++) s[r] = f2bf((c4[r] + bv[r]) * 0.125f);
                    *(s16x4*)(O + (long)m * 768 + n) = s;
                } else if (n < 1536) {
                    floatx4 bv = *(const floatx4*)(bias1 + (n - 768));
                    s16x4 s;
                    #pragma unroll
                    for (int r = 0; r < 4; r++) s[r] = f2bf(c4[r] + bv[r]);
                    *(s16x4*)(kout + (long)m * 768 + (n - 768)) = s;
                } else {
                    floatx4 bv = *(const floatx4*)(bias2 + (n - 1536));
                    s16x4 s;
                    #pragma unroll
                    for (int r = 0; r < 4; r++) s[r] = f2bf(c4[r] + bv[r]);
                    *(s16x4*)(vout + (long)m * 768 + (n - 1536)) = s;
                }
            } else if constexpr (EPI == EPI_RES) {
                floatx4 bv = *(const floatx4*)(bias0 + n);
                floatx4* hp = (floatx4*)(hres + (long)m * 768 + n);
                floatx4 hv = *hp;
                #pragma unroll
                for (int r = 0; r < 4; r++) hv[r] += c4[r] + bv[r];
                *hp = hv;
            } else if constexpr (EPI == EPI_GELU) {
                floatx4 bv = *(const floatx4*)(bias0 + n);
                s16x4 s;
                #pragma unroll
                for (int r = 0; r < 4; r++) s[r] = f2bf(gelu_f(c4[r] + bv[r]));
                *(s16x4*)(O + (long)m * ldo + n) = s;
            } else if constexpr (EPI == EPI_PATCH) {
                const int tok = m % SP;
                floatx4 v = floatx4{0.f, 0.f, 0.f, 0.f};
                if (tok >= 1 && tok < 1025) {
                    floatx4 bv = *(const floatx4*)(bias0 + n);
                    floatx4 pv = *(const floatx4*)(pos + (long)tok * 768 + n);
                    #pragma unroll
                    for (int r = 0; r < 4; r++) v[r] = c4[r] + bv[r] + pv[r];
                }
                *(floatx4*)(hres + (long)m * 768 + n) = v;
            }
        }
    }
}

// ------------------------------------------------------------
// flash attention: one block = 64 Q rows of one (b,h); 4 waves x 16 rows.
// Online softmax over 17 K-tiles of 64 (mask s >= 1025). Q pre-scaled 1/8.
// ------------------------------------------------------------
__global__ __launch_bounds__(256)
void flash_attn(const short* __restrict__ qb, const short* __restrict__ kb,
                const short* __restrict__ vt, short* __restrict__ ctx)
{
    __shared__ __align__(16) short Ks[2][4096];
    __shared__ __align__(16) short Vs[2][4096];
    __shared__ __align__(16) short Ps[4][1280];

    const int tid = threadIdx.x;
    const int wave = tid >> 6, lane = tid & 63;
    const int quad = lane >> 4, l15 = lane & 15;
    const int bh = blockIdx.y, b = bh / 12, hh = bh - b * 12;
    const int q0 = blockIdx.x * 64;

    const long krow0 = (long)(b * SP) * 768 + hh * 64;
    const long vrow0 = (long)(bh * 64) * SP;
    const int srow = tid >> 2, scol8 = tid & 3;

    short8 qa[2];
    {
        const int qrow = b * SP + q0 + wave * 16 + l15;
        const short* qp = qb + (long)qrow * 768 + hh * 64 + quad * 8;
        qa[0] = *(const short8*)qp;
        qa[1] = *(const short8*)(qp + 32);
    }

    floatx4 acco[4];
    #pragma unroll
    for (int j = 0; j < 4; j++) acco[j] = floatx4{0.f, 0.f, 0.f, 0.f};
    float m_i[4], l_i[4];
    #pragma unroll
    for (int r = 0; r < 4; r++) { m_i[r] = -1e30f; l_i[r] = 0.f; }

    auto stage = [&](int kt, int buf) {
        #pragma unroll
        for (int it = 0; it < 2; it++) {
            const short* kg = kb + krow0 + (long)(kt * 64 + srow) * 768 + it * 32 + scol8 * 8;
            gload_lds16(kg, (char*)&Ks[buf][0] + (it * 256 + wave * 64) * 16);
            const short* vg = vt + vrow0 + (long)srow * SP + kt * 64 + it * 32 + scol8 * 8;
            gload_lds16(vg, (char*)&Vs[buf][0] + (it * 256 + wave * 64) * 16);
        }
    };

    stage(0, 0);
    for (int kt = 0; kt < 17; kt++) {
        const int cur = kt & 1;
        __syncthreads();
        if (kt + 1 < 17) stage(kt + 1, cur ^ 1);

        floatx4 accs[4];
        #pragma unroll
        for (int j = 0; j < 4; j++) accs[j] = floatx4{0.f, 0.f, 0.f, 0.f};
        #pragma unroll
        for (int c = 0; c < 2; c++)
            #pragma unroll
            for (int j = 0; j < 4; j++) {
                short8 kf = *(const short8*)&Ks[cur][c * 2048 + (j * 16 + l15) * 32 + quad * 8];
                accs[j] = __builtin_amdgcn_mfma_f32_16x16x32_bf16(qa[c], kf, accs[j], 0, 0, 0);
            }
        if (kt == 16) {
            #pragma unroll
            for (int j = 0; j < 4; j++)
                if (j != 0 || l15 != 0) {
                    #pragma unroll
                    for (int r = 0; r < 4; r++) accs[j][r] = -1e30f;
                }
        }

        float alpha[4], rs[4];
        #pragma unroll
        for (int r = 0; r < 4; r++) {
            float mx = fmaxf(fmaxf(accs[0][r], accs[1][r]), fmaxf(accs[2][r], accs[3][r]));
            #pragma unroll
            for (int off = 1; off < 16; off <<= 1) mx = fmaxf(mx, __shfl_xor(mx, off, 64));
            float newm = fmaxf(m_i[r], mx);
            alpha[r] = __expf(m_i[r] - newm);
            m_i[r] = newm;
            rs[r] = 0.f;
        }
        #pragma unroll
        for (int j = 0; j < 4; j++)
            #pragma unroll
            for (int r = 0; r < 4; r++) {
                float p = __expf(accs[j][r] - m_i[r]);
                rs[r] += p;
                Ps[wave][(j >> 1) * 640 + (quad * 4 + r) * 40 + (j & 1) * 16 + l15] = f2bf(p);
            }
        #pragma unroll
        for (int r = 0; r < 4; r++) {
            float s = rs[r];
            #pragma unroll
            for (int off = 1; off < 16; off <<= 1) s += __shfl_xor(s, off, 64);
            l_i[r] = alpha[r] * l_i[r] + s;
        }
        #pragma unroll
        for (int j = 0; j < 4; j++)
            #pragma unroll
            for (int r = 0; r < 4; r++) acco[j][r] *= alpha[r];

        __syncthreads();

        #pragma unroll
        for (int c = 0; c < 2; c++) {
            short8 pa = *(const short8*)&Ps[wave][c * 640 + l15 * 40 + quad * 8];
            #pragma unroll
            for (int j = 0; j < 4; j++) {
                short8 vf = *(const short8*)&Vs[cur][c * 2048 + (j * 16 + l15) * 32 + quad * 8];
                acco[j] = __builtin_amdgcn_mfma_f32_16x16x32_bf16(pa, vf, acco[j], 0, 0, 0);
            }
        }
    }

    const int orow = b * SP + q0 + wave * 16 + quad * 4;
    #pragma unroll
    for (int r = 0; r < 4; r++) {
        float inv = 1.f / l_i[r];
        #pragma unroll
        for (int j = 0; j < 4; j++)
            ctx[(long)(orow + r) * 768 + hh * 64 + j * 16 + l15] = f2bf(acco[j][r] * inv);
    }
}

// ------------------------------------------------------------
__global__ void wtrans(const float* __restrict__ in, long inls, int K, int N,
                       short* __restrict__ out, long outls, int rowoff)
{
    in  += (long)blockIdx.z * inls;
    out += (long)blockIdx.z * outls;
    const int k0 = blockIdx.x * 32, n0 = blockIdx.y * 32;
    const int tx = threadIdx.x & 31, ty = threadIdx.x >> 5;
    __shared__ float t[32][33];
    #pragma unroll
    for (int i = 0; i < 4; i++)
        t[ty + i * 8][tx] = in[(long)(k0 + ty + i * 8) * N + n0 + tx];
    __syncthreads();
    #pragma unroll
    for (int i = 0; i < 4; i++)
        out[(long)(rowoff + n0 + ty + i * 8) * K + k0 + tx] = f2bf(t[tx][ty + i * 8]);
}

__global__ void f2b_k(const float* __restrict__ in, short* __restrict__ out, long n)
{
    long gid = (long)blockIdx.x * 256 + threadIdx.x;
    if (gid < n) out[gid] = f2bf(in[gid]);
}

__global__ void patch_gather(const float* __restrict__ x, short* __restrict__ out)
{
    long gid = (long)blockIdx.x * 256 + threadIdx.x;
    int m = (int)(gid / 768), k = (int)(gid % 768);
    int b = m / SP, tok = m - b * SP;
    short v = 0;
    if (tok >= 1 && tok < 1025) {
        int pidx = tok - 1, py = pidx >> 5, px = pidx & 31;
        int c = k >> 8, rem = k & 255, ii = rem >> 4, jj = rem & 15;
        float f = x[((long)(b * 3 + c) * 512 + py * 16 + ii) * 512 + px * 16 + jj];
        v = f2bf(f);
    }
    out[gid] = v;
}

__global__ void cls_fix(const float* __restrict__ cls, const float* __restrict__ pos,
                        float* __restrict__ h)
{
    int t = blockIdx.x * 256 + threadIdx.x;
    if (t >= 4 * 768) return;
    int b = t / 768, d = t % 768;
    h[(long)b * SP * 768 + d] = cls[d] + pos[d];
}

__global__ void ln_k(const float* __restrict__ h, const float* __restrict__ g,
                     const float* __restrict__ bta, short* __restrict__ out)
{
    int row = blockIdx.x * 4 + (threadIdx.x >> 6);
    int lane = threadIdx.x & 63;
    const float* hr = h + (long)row * 768;
    float v[12], s = 0.f;
    #pragma unroll
    for (int i = 0; i < 12; i++) { v[i] = hr[i * 64 + lane]; s += v[i]; }
    #pragma unroll
    for (int o = 32; o > 0; o >>= 1) s += __shfl_xor(s, o, 64);
    float mean = s * (1.f / 768.f);
    float ss = 0.f;
    #pragma unroll
    for (int i = 0; i < 12; i++) { float d = v[i] - mean; ss += d * d; }
    #pragma unroll
    for (int o = 32; o > 0; o >>= 1) ss += __shfl_xor(ss, o, 64);
    float rstd = rsqrtf(ss * (1.f / 768.f) + 1e-5f);
    #pragma unroll
    for (int i = 0; i < 12; i++) {
        int col = i * 64 + lane;
        out[(long)row * 768 + col] = f2bf((v[i] - mean) * rstd * g[col] + bta[col]);
    }
}

__global__ void vtrans(const short* __restrict__ v, short* __restrict__ vt)
{
    int bh = blockIdx.y, b = bh / 12, hh = bh % 12;
    int s0 = blockIdx.x * 64;
    int tx = threadIdx.x & 63, ty = threadIdx.x >> 6;
    __shared__ short t[64][65];
    #pragma unroll
    for (int i = 0; i < 16; i++) {
        int sl = ty * 16 + i;
        t[sl][tx] = v[(long)(b * SP + s0 + sl) * 768 + hh * 64 + tx];
    }
    __syncthreads();
    #pragma unroll
    for (int i = 0; i < 16; i++) {
        int d = ty * 16 + i;
        vt[((long)bh * 64 + d) * SP + s0 + tx] = t[tx][d];
    }
}

// wave-per-row logits: 4 waves/block, lane-parallel over K=384, shfl reduce.
__global__ void logits_k(const short* __restrict__ hid, const float* __restrict__ w2,
                         const float* __restrict__ b2, float* __restrict__ o, int NO)
{
    int row = blockIdx.x * 4 + (threadIdx.x >> 6);   // 0..4099 (grid 1025)
    int lane = threadIdx.x & 63;
    int b = row / 1025, s = row - b * 1025;
    const short* hr = hid + (long)(b * SP + s) * 384;
    float v[6];
    #pragma unroll
    for (int i = 0; i < 6; i++) v[i] = bf2f(hr[i * 64 + lane]);
    for (int n = 0; n < NO; n++) {
        float a = 0.f;
        #pragma unroll
        for (int i = 0; i < 6; i++) a += v[i] * w2[(i * 64 + lane) * NO + n];
        #pragma unroll
        for (int off = 32; off > 0; off >>= 1) a += __shfl_xor(a, off, 64);
        if (lane == 0) o[row * NO + n] = a + b2[n];
    }
}

__global__ void feats_out(const float* __restrict__ h, float* __restrict__ o)
{
    int gid = blockIdx.x * 256 + threadIdx.x;
    if (gid >= 4 * 1025 * 192) return;
    int row = gid / 192, c4 = gid % 192;
    int b = row / 1025, s = row % 1025;
    const float4* src = (const float4*)(h + (long)(b * SP + s) * 768) + c4;
    float4* dst = (float4*)(o + (long)row * 768) + c4;
    *dst = *src;
}

// ============================================================
extern "C" void kernel_launch(void* const* d_in, const int* in_sizes, int n_in,
                              void* d_out, int out_size, void* d_ws, size_t ws_size,
                              hipStream_t stream)
{
    const float* x       = (const float*)d_in[0];
    const float* conv_w  = (const float*)d_in[1];
    const float* conv_b  = (const float*)d_in[2];
    const float* cls_tok = (const float*)d_in[3];
    const float* pos_emb = (const float*)d_in[4];
    const float* ln1g = (const float*)d_in[5];
    const float* ln1b = (const float*)d_in[6];
    const float* wq = (const float*)d_in[7];
    const float* bq = (const float*)d_in[8];
    const float* wk = (const float*)d_in[9];
    const float* bk = (const float*)d_in[10];
    const float* wv = (const float*)d_in[11];
    const float* bv = (const float*)d_in[12];
    const float* wo = (const float*)d_in[13];
    const float* bo = (const float*)d_in[14];
    const float* ln2g = (const float*)d_in[15];
    const float* ln2b = (const float*)d_in[16];
    const float* w1 = (const float*)d_in[17];
    const float* b1 = (const float*)d_in[18];
    const float* w2 = (const float*)d_in[19];
    const float* b2 = (const float*)d_in[20];
    const float* cwq = (const float*)d_in[21];
    const float* cbq = (const float*)d_in[22];
    const float* cwk = (const float*)d_in[23];
    const float* cbk = (const float*)d_in[24];
    const float* cwv = (const float*)d_in[25];
    const float* cbv = (const float*)d_in[26];
    const float* cwo = (const float*)d_in[27];
    const float* cbo = (const float*)d_in[28];
    const float* fh_w1 = (const float*)d_in[29];
    const float* fh_b1 = (const float*)d_in[30];
    const float* fh_w2 = (const float*)d_in[31];
    const float* fh_b2 = (const float*)d_in[32];
    const float* vh_w1 = (const float*)d_in[33];
    const float* vh_b1 = (const float*)d_in[34];
    const float* vh_w2 = (const float*)d_in[35];
    const float* vh_b2 = (const float*)d_in[36];
    const float* ch_w1 = (const float*)d_in[37];
    const float* ch_b1 = (const float*)d_in[38];
    const float* ch_w2 = (const float*)d_in[39];
    const float* ch_b2 = (const float*)d_in[40];
    float* out = (float*)d_out;

    // ---- workspace carve-up (M = 4*SP = 4352 rows) ----
    char* ws = (char*)d_ws;
    size_t off = 0;
    auto alc = [&](size_t b) { char* p = ws + off; off += (b + 255) & ~(size_t)255; return p; };
    float* h     = (float*)alc(4352L * 768 * 4);
    short* abuf  = (short*)alc(4352L * 768 * 2);
    short* gbuf  = (short*)alc(4352L * 3072 * 2);
    short* qb    = (short*)alc(4352L * 768 * 2);
    short* kb    = (short*)alc(4352L * 768 * 2);
    short* vb    = (short*)alc(4352L * 768 * 2);
    short* vt    = (short*)alc(48L * 64 * SP * 2);
    short* ctx   = (short*)alc(4352L * 768 * 2);
    short* fbuf  = (short*)alc(4352L * 768 * 2);
    short* vfbuf = (short*)alc(4352L * 768 * 2);
    short* hid   = (short*)alc(4352L * 384 * 2);
    short* wqkvT = (short*)alc(12L * 2304 * 768 * 2);
    short* woT   = (short*)alc(12L * 768 * 768 * 2);
    short* w1T   = (short*)alc(12L * 3072 * 768 * 2);
    short* w2T   = (short*)alc(12L * 768 * 3072 * 2);
    short* convT = (short*)alc(768L * 768 * 2);
    short* cqkvT = (short*)alc(2304L * 768 * 2);
    short* coT   = (short*)alc(768L * 768 * 2);
    short* fh1T  = (short*)alc(384L * 768 * 2);
    short* vh1T  = (short*)alc(384L * 768 * 2);
    short* ch1T  = (short*)alc(384L * 768 * 2);
    short* dummy = (short*)d_ws;

    // ---- weight prep (bf16 transposed [N,K]) ----
    wtrans<<<dim3(24, 24, 12), 256, 0, stream>>>(wq, 589824L, 768, 768, wqkvT, 1769472L, 0);
    wtrans<<<dim3(24, 24, 12), 256, 0, stream>>>(wk, 589824L, 768, 768, wqkvT, 1769472L, 768);
    wtrans<<<dim3(24, 24, 12), 256, 0, stream>>>(wv, 589824L, 768, 768, wqkvT, 1769472L, 1536);
    wtrans<<<dim3(24, 24, 12), 256, 0, stream>>>(wo, 589824L, 768, 768, woT, 589824L, 0);
    wtrans<<<dim3(24, 96, 12), 256, 0, stream>>>(w1, 2359296L, 768, 3072, w1T, 2359296L, 0);
    wtrans<<<dim3(96, 24, 12), 256, 0, stream>>>(w2, 2359296L, 3072, 768, w2T, 2359296L, 0);
    wtrans<<<dim3(24, 24, 1), 256, 0, stream>>>(cwq, 0, 768, 768, cqkvT, 0, 0);
    wtrans<<<dim3(24, 24, 1), 256, 0, stream>>>(cwk, 0, 768, 768, cqkvT, 0, 768);
    wtrans<<<dim3(24, 24, 1), 256, 0, stream>>>(cwv, 0, 768, 768, cqkvT, 0, 1536);
    wtrans<<<dim3(24, 24, 1), 256, 0, stream>>>(cwo, 0, 768, 768, coT, 0, 0);
    wtrans<<<dim3(24, 12, 1), 256, 0, stream>>>(fh_w1, 0, 768, 384, fh1T, 0, 0);
    wtrans<<<dim3(24, 12, 1), 256, 0, stream>>>(vh_w1, 0, 768, 384, vh1T, 0, 0);
    wtrans<<<dim3(24, 12, 1), 256, 0, stream>>>(ch_w1, 0, 768, 384, ch1T, 0, 0);
    f2b_k<<<2304, 256, 0, stream>>>(conv_w, convT, 589824L);

    // ---- patch embedding ----
    patch_gather<<<13056, 256, 0, stream>>>(x, abuf);
    gemm_bt<64, EPI_PATCH><<<dim3(34, 12), 256, 0, stream>>>(
        abuf, 768, convT, 768, 768,
        dummy, 768, conv_b, nullptr, nullptr, h, pos_emb, nullptr, nullptr);
    cls_fix<<<12, 256, 0, stream>>>(cls_tok, pos_emb, h);

    // ---- transformer blocks ----
    for (int l = 0; l < 12; l++) {
        ln_k<<<1088, 256, 0, stream>>>(h, ln1g + l * 768, ln1b + l * 768, abuf);
        gemm_bt<128, EPI_QKV><<<dim3(34, 18), 256, 0, stream>>>(
            abuf, 768, wqkvT + (long)l * 2304 * 768, 768, 768,
            qb, 768, bq + l * 768, bk + l * 768, bv + l * 768,
            nullptr, nullptr, kb, vb);
        vtrans<<<dim3(17, 48), 256, 0, stream>>>(vb, vt);
        flash_attn<<<dim3(17, 48), 256, 0, stream>>>(qb, kb, vt, ctx);
        gemm_bt<64, EPI_RES><<<dim3(34, 12), 256, 0, stream>>>(
            ctx, 768, woT + (long)l * 768 * 768, 768, 768,
            dummy, 768, bo + l * 768, nullptr, nullptr, h, nullptr, nullptr, nullptr);
        ln_k<<<1088, 256, 0, stream>>>(h, ln2g + l * 768, ln2b + l * 768, abuf);
        gemm_bt<128, EPI_GELU><<<dim3(34, 24), 256, 0, stream>>>(
            abuf, 768, w1T + (long)l * 3072 * 768, 768, 768,
            gbuf, 3072, b1 + l * 3072, nullptr, nullptr, nullptr, nullptr, nullptr, nullptr);
        gemm_bt<64, EPI_RES><<<dim3(34, 12), 256, 0, stream>>>(
            gbuf, 3072, w2T + (long)l * 768 * 3072, 3072, 3072,
            dummy, 768, b2 + l * 768, nullptr, nullptr, h, nullptr, nullptr, nullptr);
    }

    // ---- cross-attention ----
    f2b_k<<<13056, 256, 0, stream>>>(h, fbuf, 4352L * 768);
    gemm_bt<128, EPI_QKV><<<dim3(34, 18), 256, 0, stream>>>(
        fbuf, 768, cqkvT, 768, 768,
        qb, 768, cbq, cbk, cbv, nullptr, nullptr, kb, vb);
    vtrans<<<dim3(17, 48), 256, 0, stream>>>(vb, vt);
    flash_attn<<<dim3(17, 48), 256, 0, stream>>>(qb, kb, vt, ctx);
    gemm_bt<64, EPI_BIAS><<<dim3(34, 12), 256, 0, stream>>>(
        ctx, 768, coT, 768, 768,
        vfbuf, 768, cbo, nullptr, nullptr, nullptr, nullptr, nullptr, nullptr);

    // ---- heads ----
    gemm_bt<64, EPI_GELU><<<dim3(34, 6), 256, 0, stream>>>(
        fbuf, 768, fh1T, 768, 768,
        hid, 384, fh_b1, nullptr, nullptr, nullptr, nullptr, nullptr, nullptr);
    logits_k<<<1025, 256, 0, stream>>>(hid, fh_w2, fh_b2, out + 0, 2);
    gemm_bt<64, EPI_GELU><<<dim3(34, 6), 256, 0, stream>>>(
        vfbuf, 768, vh1T, 768, 768,
        hid, 384, vh_b1, nullptr, nullptr, nullptr, nullptr, nullptr, nullptr);
    logits_k<<<1025, 256, 0, stream>>>(hid, vh_w2, vh_b2, out + 8200, 4);
    gemm_bt<64, EPI_GELU><<<dim3(34, 6), 256, 0, stream>>>(
        vfbuf, 768, ch1T, 768, 768,
        hid, 384, ch_b1, nullptr, nullptr, nullptr, nullptr, nullptr, nullptr);
    logits_k<<<1025, 256, 0, stream>>>(hid, ch_w2, ch_b2, out + 24600, 3);

    feats_out<<<3075, 256, 0, stream>>>(h, out + 36900);

    (void)in_sizes; (void)n_in; (void)out_size; (void)ws_size;
}

// Round 2
// 3378.627 us; speedup vs baseline: 1.0329x; 1.0329x over previous
//
#include <hip/hip_runtime.h>

// ============================================================
// CustomUltrasoundViT: 12-layer ViT (B=4, S=1025->pad 1088=17*64, D=768, H=12,
// HD=64, MLP=3072) + cross-attn + 3 heads. bf16 MFMA GEMMs, fp32 residual.
// R4: pad 1088; operand-swapped MFMA -> vectorized epilogues; wave logits.
// R5: (a) XOR bank-swizzle on all MFMA LDS tiles (K/V in flash via pre-swizzled
// global source since global_load_lds writes linearly; As/Bs in gemm via
// swizzled ds_write slot) -- kills the 4-way conflict on every ds_read_b128;
// (b) drop flash's mid-iteration barrier (Ps is wave-private; replaces a full
// vmcnt-drain of the freshly issued prefetch with an in-wave lgkmcnt(0));
// (c) exp2-domain softmax (1/ln2 folded into Q scale) + row-sum l via
// ones-column MFMA instead of 16 adds + 4-step shfl reduce.
// ============================================================

#define SP 1088   // padded sequence length (17*64)

typedef __attribute__((ext_vector_type(8))) short short8;
typedef __attribute__((ext_vector_type(4))) short s16x4;
typedef __attribute__((ext_vector_type(4))) float floatx4;

#define EPI_BF16  0
#define EPI_BIAS  1
#define EPI_QKV   2
#define EPI_RES   3
#define EPI_GELU  4
#define EPI_PATCH 5

// 0.125 (1/sqrt(64)) * log2(e): Q pre-scale so softmax runs in exp2 domain
#define QSCALE 0.18033688011112042f

__device__ __forceinline__ short f2bf(float f) {
    union { float f; unsigned u; } x; x.f = f;
    return (short)((x.u + 0x7fffu + ((x.u >> 16) & 1u)) >> 16);
}
__device__ __forceinline__ float bf2f(short s) {
    union { unsigned u; float f; } x; x.u = ((unsigned)(unsigned short)s) << 16;
    return x.f;
}
__device__ __forceinline__ float gelu_f(float x) {
    return 0.5f * x * (1.f + erff(x * 0.70710678118654752f));
}
__device__ __forceinline__ void gload_lds16(const void* g, void* l) {
    __builtin_amdgcn_global_load_lds((const __attribute__((address_space(1))) void*)g,
                                     (__attribute__((address_space(3))) void*)l, 16, 0, 0);
}

// ------------------------------------------------------------
// gemm_bt: C[M,N] = A[M,K] @ BT[N,K]^T (row-major bf16-as-short).
// BM=128. K-loop: global->VGPR prefetch (2 tiles deep, survives barriers) ->
// swizzled ds_write -> single barrier -> swizzled ds_read frags -> MFMA.
// LDS slot swizzle: slot ^= (row>>1)&3  (8-short slots within 32-short rows)
// -> conflict-free b128 reads (was 4-way: row stride 64B).
// ------------------------------------------------------------
template<int BN, int EPI>
__global__ __launch_bounds__(256)
void gemm_bt(const short* __restrict__ A, int lda,
             const short* __restrict__ Bt, int ldb, int K,
             short* __restrict__ O, int ldo,
             const float* __restrict__ bias0, const float* __restrict__ bias1,
             const float* __restrict__ bias2, float* __restrict__ hres,
             const float* __restrict__ pos,
             short* __restrict__ kout, short* __restrict__ vout)
{
    constexpr int BCH = BN / 64;                 // B-tile 16B chunks per thread
    constexpr int WNS = (BN == 128) ? 64 : 32;   // wave N span
    constexpr int NJ  = WNS / 16;
    __shared__ __align__(16) short As[2][128 * 32];
    __shared__ __align__(16) short Bs[2][BN * 32];

    const int tid = threadIdx.x;
    const int m0 = blockIdx.x * 128, n0 = blockIdx.y * BN;
    const int wave = tid >> 6, lane = tid & 63;
    const int quad = lane >> 4, l15 = lane & 15;
    const int wm = wave >> 1, wn = wave & 1;
    const int srow = tid >> 2, scol = (tid & 3) * 8;
    const int sslot8 = ((tid & 3) ^ ((srow >> 1) & 3)) * 8;   // swizzled LDS write slot
    const int rsw = (l15 >> 1) & 3;                            // read-side swizzle

    const short* Ag = A + (long)(m0 + srow) * lda + scol;
    const short* Bg = Bt + (long)(n0 + srow) * ldb + scol;

    const int NIT = K >> 5;                      // always even, >= 12
    short8 ra[2][2], rb[2][BCH];
    #pragma unroll
    for (int pp = 0; pp < 2; pp++) {
        #pragma unroll
        for (int c = 0; c < 2; c++)
            ra[pp][c] = *(const short8*)(Ag + (long)(64 * c) * lda + pp * 32);
        #pragma unroll
        for (int c = 0; c < BCH; c++)
            rb[pp][c] = *(const short8*)(Bg + (long)(64 * c) * ldb + pp * 32);
    }

    floatx4 acc[4][NJ];
    #pragma unroll
    for (int i = 0; i < 4; i++)
        #pragma unroll
        for (int j = 0; j < NJ; j++)
            acc[i][j] = floatx4{0.f, 0.f, 0.f, 0.f};

    auto step = [&](int it, int pp) {
        short* as = As[pp];
        short* bs = Bs[pp];
        // regs -> LDS (tile it), swizzled slot
        #pragma unroll
        for (int c = 0; c < 2; c++)
            *(short8*)&as[(srow + 64 * c) * 32 + sslot8] = ra[pp][c];
        #pragma unroll
        for (int c = 0; c < BCH; c++)
            *(short8*)&bs[(srow + 64 * c) * 32 + sslot8] = rb[pp][c];
        __syncthreads();
        // issue global loads for tile it+2 (private regs: not drained by barriers)
        if (it + 2 < NIT) {
            const int k0 = (it + 2) * 32;
            #pragma unroll
            for (int c = 0; c < 2; c++)
                ra[pp][c] = *(const short8*)(Ag + (long)(64 * c) * lda + k0);
            #pragma unroll
            for (int c = 0; c < BCH; c++)
                rb[pp][c] = *(const short8*)(Bg + (long)(64 * c) * ldb + k0);
        }
        // LDS -> frags -> MFMA (swapped operands: acc holds C^T fragments)
        short8 af[4], bfrag[NJ];
        #pragma unroll
        for (int i = 0; i < 4; i++)
            af[i] = *(const short8*)&as[(wm * 64 + i * 16 + l15) * 32 + (quad ^ rsw) * 8];
        #pragma unroll
        for (int j = 0; j < NJ; j++)
            bfrag[j] = *(const short8*)&bs[(wn * WNS + j * 16 + l15) * 32 + (quad ^ rsw) * 8];
        #pragma unroll
        for (int i = 0; i < 4; i++)
            #pragma unroll
            for (int j = 0; j < NJ; j++)
                acc[i][j] = __builtin_amdgcn_mfma_f32_16x16x32_bf16(bfrag[j], af[i], acc[i][j], 0, 0, 0);
        // no trailing barrier: next iter writes the other LDS buffer
    };

    #pragma unroll 1
    for (int it = 0; it < NIT; it += 2) {
        step(it, 0);
        step(it + 1, 1);
    }

    // epilogue: thread (quad,l15) holds C[m = .. + l15][n = .. + quad*4 + r]
    const int mb = m0 + wm * 64 + l15;
    const int nbase = n0 + wn * WNS + quad * 4;
    #pragma unroll
    for (int i = 0; i < 4; i++) {
        const int m = mb + i * 16;
        #pragma unroll
        for (int j = 0; j < NJ; j++) {
            const int n = nbase + j * 16;
            floatx4 c4 = acc[i][j];
            if constexpr (EPI == EPI_BF16) {
                s16x4 s;
                #pragma unroll
                for (int r = 0; r < 4; r++) s[r] = f2bf(c4[r]);
                *(s16x4*)(O + (long)m * ldo + n) = s;
            } else if constexpr (EPI == EPI_BIAS) {
                floatx4 bv = *(const floatx4*)(bias0 + n);
                s16x4 s;
                #pragma unroll
                for (int r = 0; r < 4; r++) s[r] = f2bf(c4[r] + bv[r]);
                *(s16x4*)(O + (long)m * ldo + n) = s;
            } else if constexpr (EPI == EPI_QKV) {
                if (n < 768) {
                    floatx4 bv = *(const floatx4*)(bias0 + n);
                    s16x4 s;
                    #pragma unroll
                    for (int r = 0; r < 4; r++) s[r] = f2bf((c4[r] + bv[r]) * QSCALE);
                    *(s16x4*)(O + (long)m * 768 + n) = s;
                } else if (n < 1536) {
                    floatx4 bv = *(const floatx4*)(bias1 + (n - 768));
                    s16x4 s;
                    #pragma unroll
                    for (int r = 0; r < 4; r++) s[r] = f2bf(c4[r] + bv[r]);
                    *(s16x4*)(kout + (long)m * 768 + (n - 768)) = s;
                } else {
                    floatx4 bv = *(const floatx4*)(bias2 + (n - 1536));
                    s16x4 s;
                    #pragma unroll
                    for (int r = 0; r < 4; r++) s[r] = f2bf(c4[r] + bv[r]);
                    *(s16x4*)(vout + (long)m * 768 + (n - 1536)) = s;
                }
            } else if constexpr (EPI == EPI_RES) {
                floatx4 bv = *(const floatx4*)(bias0 + n);
                floatx4* hp = (floatx4*)(hres + (long)m * 768 + n);
                floatx4 hv = *hp;
                #pragma unroll
                for (int r = 0; r < 4; r++) hv[r] += c4[r] + bv[r];
                *hp = hv;
            } else if constexpr (EPI == EPI_GELU) {
                floatx4 bv = *(const floatx4*)(bias0 + n);
                s16x4 s;
                #pragma unroll
                for (int r = 0; r < 4; r++) s[r] = f2bf(gelu_f(c4[r] + bv[r]));
                *(s16x4*)(O + (long)m * ldo + n) = s;
            } else if constexpr (EPI == EPI_PATCH) {
                const int tok = m % SP;
                floatx4 v = floatx4{0.f, 0.f, 0.f, 0.f};
                if (tok >= 1 && tok < 1025) {
                    floatx4 bv = *(const floatx4*)(bias0 + n);
                    floatx4 pv = *(const floatx4*)(pos + (long)tok * 768 + n);
                    #pragma unroll
                    for (int r = 0; r < 4; r++) v[r] = c4[r] + bv[r] + pv[r];
                }
                *(floatx4*)(hres + (long)m * 768 + n) = v;
            }
        }
    }
}

// ------------------------------------------------------------
// flash attention: one block = 64 Q rows of one (b,h); 4 waves x 16 rows.
// Online softmax (exp2 domain; Q pre-scaled 0.125*log2e) over 17 K-tiles of 64
// (mask s >= 1025). K/V LDS tiles bank-swizzled via pre-swizzled global source
// (global_load_lds writes linearly). One barrier per iter; Ps is wave-private
// so PV only needs an in-wave lgkmcnt(0). Row-sum l via ones-column MFMA.
// ------------------------------------------------------------
__global__ __launch_bounds__(256)
void flash_attn(const short* __restrict__ qb, const short* __restrict__ kb,
                const short* __restrict__ vt, short* __restrict__ ctx)
{
    __shared__ __align__(16) short Ks[2][4096];
    __shared__ __align__(16) short Vs[2][4096];
    __shared__ __align__(16) short Ps[4][1280];

    const int tid = threadIdx.x;
    const int wave = tid >> 6, lane = tid & 63;
    const int quad = lane >> 4, l15 = lane & 15;
    const int bh = blockIdx.y, b = bh / 12, hh = bh - b * 12;
    const int q0 = blockIdx.x * 64;

    const long krow0 = (long)(b * SP) * 768 + hh * 64;
    const long vrow0 = (long)(bh * 64) * SP;
    const int srow = tid >> 2;
    const int scol8 = (tid & 3) ^ ((srow >> 1) & 3);   // pre-swizzled source slot
    const int rsw = (l15 >> 1) & 3;                     // read-side swizzle

    short8 qa[2];
    {
        const int qrow = b * SP + q0 + wave * 16 + l15;
        const short* qp = qb + (long)qrow * 768 + hh * 64 + quad * 8;
        qa[0] = *(const short8*)qp;
        qa[1] = *(const short8*)(qp + 32);
    }

    // ones-column B-frag for row-sum via MFMA (col 0 only)
    const short ov = (l15 == 0) ? (short)0x3F80 : (short)0;
    const short8 vones = {ov, ov, ov, ov, ov, ov, ov, ov};

    floatx4 acco[4];
    #pragma unroll
    for (int j = 0; j < 4; j++) acco[j] = floatx4{0.f, 0.f, 0.f, 0.f};
    floatx4 accl = floatx4{0.f, 0.f, 0.f, 0.f};
    float m_i[4];
    #pragma unroll
    for (int r = 0; r < 4; r++) m_i[r] = -1e30f;

    auto stage = [&](int kt, int buf) {
        #pragma unroll
        for (int it = 0; it < 2; it++) {
            const short* kg = kb + krow0 + (long)(kt * 64 + srow) * 768 + it * 32 + scol8 * 8;
            gload_lds16(kg, (char*)&Ks[buf][0] + (it * 256 + wave * 64) * 16);
            const short* vg = vt + vrow0 + (long)srow * SP + kt * 64 + it * 32 + scol8 * 8;
            gload_lds16(vg, (char*)&Vs[buf][0] + (it * 256 + wave * 64) * 16);
        }
    };

    stage(0, 0);
    for (int kt = 0; kt < 17; kt++) {
        const int cur = kt & 1;
        __syncthreads();               // staging of tile kt complete (vmcnt drain)
        if (kt + 1 < 17) stage(kt + 1, cur ^ 1);   // in flight until next barrier

        floatx4 accs[4];
        #pragma unroll
        for (int j = 0; j < 4; j++) accs[j] = floatx4{0.f, 0.f, 0.f, 0.f};
        #pragma unroll
        for (int c = 0; c < 2; c++)
            #pragma unroll
            for (int j = 0; j < 4; j++) {
                short8 kf = *(const short8*)&Ks[cur][c * 2048 + (j * 16 + l15) * 32 + (quad ^ rsw) * 8];
                accs[j] = __builtin_amdgcn_mfma_f32_16x16x32_bf16(qa[c], kf, accs[j], 0, 0, 0);
            }
        if (kt == 16) {
            #pragma unroll
            for (int j = 0; j < 4; j++)
                if (j != 0 || l15 != 0) {
                    #pragma unroll
                    for (int r = 0; r < 4; r++) accs[j][r] = -1e30f;
                }
        }

        float alpha[4];
        #pragma unroll
        for (int r = 0; r < 4; r++) {
            float mx = fmaxf(fmaxf(accs[0][r], accs[1][r]), fmaxf(accs[2][r], accs[3][r]));
            #pragma unroll
            for (int off = 1; off < 16; off <<= 1) mx = fmaxf(mx, __shfl_xor(mx, off, 64));
            float newm = fmaxf(m_i[r], mx);
            alpha[r] = exp2f(m_i[r] - newm);
            m_i[r] = newm;
        }
        #pragma unroll
        for (int j = 0; j < 4; j++)
            #pragma unroll
            for (int r = 0; r < 4; r++) {
                float p = exp2f(accs[j][r] - m_i[r]);
                Ps[wave][(j >> 1) * 640 + (quad * 4 + r) * 40 + (j & 1) * 16 + l15] = f2bf(p);
            }
        #pragma unroll
        for (int j = 0; j < 4; j++)
            #pragma unroll
            for (int r = 0; r < 4; r++) acco[j][r] *= alpha[r];
        #pragma unroll
        for (int r = 0; r < 4; r++) accl[r] *= alpha[r];

        // Ps is wave-private: in-wave DS ordering only (no block barrier;
        // keeps the stage(kt+1) prefetch in flight through PV)
        asm volatile("s_waitcnt lgkmcnt(0)" ::: "memory");
        __builtin_amdgcn_sched_barrier(0);

        #pragma unroll
        for (int c = 0; c < 2; c++) {
            short8 pa = *(const short8*)&Ps[wave][c * 640 + l15 * 40 + quad * 8];
            #pragma unroll
            for (int j = 0; j < 4; j++) {
                short8 vf = *(const short8*)&Vs[cur][c * 2048 + (j * 16 + l15) * 32 + (quad ^ rsw) * 8];
                acco[j] = __builtin_amdgcn_mfma_f32_16x16x32_bf16(pa, vf, acco[j], 0, 0, 0);
            }
            accl = __builtin_amdgcn_mfma_f32_16x16x32_bf16(pa, vones, accl, 0, 0, 0);
        }
    }

    const int orow = b * SP + q0 + wave * 16 + quad * 4;
    #pragma unroll
    for (int r = 0; r < 4; r++) {
        float lsum = __shfl(accl[r], (lane & 48), 64);   // l lives at l15==0 of same quad
        float inv = 1.f / lsum;
        #pragma unroll
        for (int j = 0; j < 4; j++)
            ctx[(long)(orow + r) * 768 + hh * 64 + j * 16 + l15] = f2bf(acco[j][r] * inv);
    }
}

// ------------------------------------------------------------
__global__ void wtrans(const float* __restrict__ in, long inls, int K, int N,
                       short* __restrict__ out, long outls, int rowoff)
{
    in  += (long)blockIdx.z * inls;
    out += (long)blockIdx.z * outls;
    const int k0 = blockIdx.x * 32, n0 = blockIdx.y * 32;
    const int tx = threadIdx.x & 31, ty = threadIdx.x >> 5;
    __shared__ float t[32][33];
    #pragma unroll
    for (int i = 0; i < 4; i++)
        t[ty + i * 8][tx] = in[(long)(k0 + ty + i * 8) * N + n0 + tx];
    __syncthreads();
    #pragma unroll
    for (int i = 0; i < 4; i++)
        out[(long)(rowoff + n0 + ty + i * 8) * K + k0 + tx] = f2bf(t[tx][ty + i * 8]);
}

__global__ void f2b_k(const float* __restrict__ in, short* __restrict__ out, long n)
{
    long gid = (long)blockIdx.x * 256 + threadIdx.x;
    if (gid < n) out[gid] = f2bf(in[gid]);
}

__global__ void patch_gather(const float* __restrict__ x, short* __restrict__ out)
{
    long gid = (long)blockIdx.x * 256 + threadIdx.x;
    int m = (int)(gid / 768), k = (int)(gid % 768);
    int b = m / SP, tok = m - b * SP;
    short v = 0;
    if (tok >= 1 && tok < 1025) {
        int pidx = tok - 1, py = pidx >> 5, px = pidx & 31;
        int c = k >> 8, rem = k & 255, ii = rem >> 4, jj = rem & 15;
        float f = x[((long)(b * 3 + c) * 512 + py * 16 + ii) * 512 + px * 16 + jj];
        v = f2bf(f);
    }
    out[gid] = v;
}

__global__ void cls_fix(const float* __restrict__ cls, const float* __restrict__ pos,
                        float* __restrict__ h)
{
    int t = blockIdx.x * 256 + threadIdx.x;
    if (t >= 4 * 768) return;
    int b = t / 768, d = t % 768;
    h[(long)b * SP * 768 + d] = cls[d] + pos[d];
}

__global__ void ln_k(const float* __restrict__ h, const float* __restrict__ g,
                     const float* __restrict__ bta, short* __restrict__ out)
{
    int row = blockIdx.x * 4 + (threadIdx.x >> 6);
    int lane = threadIdx.x & 63;
    const float* hr = h + (long)row * 768;
    float v[12], s = 0.f;
    #pragma unroll
    for (int i = 0; i < 12; i++) { v[i] = hr[i * 64 + lane]; s += v[i]; }
    #pragma unroll
    for (int o = 32; o > 0; o >>= 1) s += __shfl_xor(s, o, 64);
    float mean = s * (1.f / 768.f);
    float ss = 0.f;
    #pragma unroll
    for (int i = 0; i < 12; i++) { float d = v[i] - mean; ss += d * d; }
    #pragma unroll
    for (int o = 32; o > 0; o >>= 1) ss += __shfl_xor(ss, o, 64);
    float rstd = rsqrtf(ss * (1.f / 768.f) + 1e-5f);
    #pragma unroll
    for (int i = 0; i < 12; i++) {
        int col = i * 64 + lane;
        out[(long)row * 768 + col] = f2bf((v[i] - mean) * rstd * g[col] + bta[col]);
    }
}

__global__ void vtrans(const short* __restrict__ v, short* __restrict__ vt)
{
    int bh = blockIdx.y, b = bh / 12, hh = bh % 12;
    int s0 = blockIdx.x * 64;
    int tx = threadIdx.x & 63, ty = threadIdx.x >> 6;
    __shared__ short t[64][65];
    #pragma unroll
    for (int i = 0; i < 16; i++) {
        int sl = ty * 16 + i;
        t[sl][tx] = v[(long)(b * SP + s0 + sl) * 768 + hh * 64 + tx];
    }
    __syncthreads();
    #pragma unroll
    for (int i = 0; i < 16; i++) {
        int d = ty * 16 + i;
        vt[((long)bh * 64 + d) * SP + s0 + tx] = t[tx][d];
    }
}

// wave-per-row logits: 4 waves/block, lane-parallel over K=384, shfl reduce.
__global__ void logits_k(const short* __restrict__ hid, const float* __restrict__ w2,
                         const float* __restrict__ b2, float* __restrict__ o, int NO)
{
    int row = blockIdx.x * 4 + (threadIdx.x >> 6);   // 0..4099 (grid 1025)
    int lane = threadIdx.x & 63;
    int b = row / 1025, s = row - b * 1025;
    const short* hr = hid + (long)(b * SP + s) * 384;
    float v[6];
    #pragma unroll
    for (int i = 0; i < 6; i++) v[i] = bf2f(hr[i * 64 + lane]);
    for (int n = 0; n < NO; n++) {
        float a = 0.f;
        #pragma unroll
        for (int i = 0; i < 6; i++) a += v[i] * w2[(i * 64 + lane) * NO + n];
        #pragma unroll
        for (int off = 32; off > 0; off >>= 1) a += __shfl_xor(a, off, 64);
        if (lane == 0) o[row * NO + n] = a + b2[n];
    }
}

__global__ void feats_out(const float* __restrict__ h, float* __restrict__ o)
{
    int gid = blockIdx.x * 256 + threadIdx.x;
    if (gid >= 4 * 1025 * 192) return;
    int row = gid / 192, c4 = gid % 192;
    int b = row / 1025, s = row % 1025;
    const float4* src = (const float4*)(h + (long)(b * SP + s) * 768) + c4;
    float4* dst = (float4*)(o + (long)row * 768) + c4;
    *dst = *src;
}

// ============================================================
extern "C" void kernel_launch(void* const* d_in, const int* in_sizes, int n_in,
                              void* d_out, int out_size, void* d_ws, size_t ws_size,
                              hipStream_t stream)
{
    const float* x       = (const float*)d_in[0];
    const float* conv_w  = (const float*)d_in[1];
    const float* conv_b  = (const float*)d_in[2];
    const float* cls_tok = (const float*)d_in[3];
    const float* pos_emb = (const float*)d_in[4];
    const float* ln1g = (const float*)d_in[5];
    const float* ln1b = (const float*)d_in[6];
    const float* wq = (const float*)d_in[7];
    const float* bq = (const float*)d_in[8];
    const float* wk = (const float*)d_in[9];
    const float* bk = (const float*)d_in[10];
    const float* wv = (const float*)d_in[11];
    const float* bv = (const float*)d_in[12];
    const float* wo = (const float*)d_in[13];
    const float* bo = (const float*)d_in[14];
    const float* ln2g = (const float*)d_in[15];
    const float* ln2b = (const float*)d_in[16];
    const float* w1 = (const float*)d_in[17];
    const float* b1 = (const float*)d_in[18];
    const float* w2 = (const float*)d_in[19];
    const float* b2 = (const float*)d_in[20];
    const float* cwq = (const float*)d_in[21];
    const float* cbq = (const float*)d_in[22];
    const float* cwk = (const float*)d_in[23];
    const float* cbk = (const float*)d_in[24];
    const float* cwv = (const float*)d_in[25];
    const float* cbv = (const float*)d_in[26];
    const float* cwo = (const float*)d_in[27];
    const float* cbo = (const float*)d_in[28];
    const float* fh_w1 = (const float*)d_in[29];
    const float* fh_b1 = (const float*)d_in[30];
    const float* fh_w2 = (const float*)d_in[31];
    const float* fh_b2 = (const float*)d_in[32];
    const float* vh_w1 = (const float*)d_in[33];
    const float* vh_b1 = (const float*)d_in[34];
    const float* vh_w2 = (const float*)d_in[35];
    const float* vh_b2 = (const float*)d_in[36];
    const float* ch_w1 = (const float*)d_in[37];
    const float* ch_b1 = (const float*)d_in[38];
    const float* ch_w2 = (const float*)d_in[39];
    const float* ch_b2 = (const float*)d_in[40];
    float* out = (float*)d_out;

    // ---- workspace carve-up (M = 4*SP = 4352 rows) ----
    char* ws = (char*)d_ws;
    size_t off = 0;
    auto alc = [&](size_t b) { char* p = ws + off; off += (b + 255) & ~(size_t)255; return p; };
    float* h     = (float*)alc(4352L * 768 * 4);
    short* abuf  = (short*)alc(4352L * 768 * 2);
    short* gbuf  = (short*)alc(4352L * 3072 * 2);
    short* qb    = (short*)alc(4352L * 768 * 2);
    short* kb    = (short*)alc(4352L * 768 * 2);
    short* vb    = (short*)alc(4352L * 768 * 2);
    short* vt    = (short*)alc(48L * 64 * SP * 2);
    short* ctx   = (short*)alc(4352L * 768 * 2);
    short* fbuf  = (short*)alc(4352L * 768 * 2);
    short* vfbuf = (short*)alc(4352L * 768 * 2);
    short* hid   = (short*)alc(4352L * 384 * 2);
    short* wqkvT = (short*)alc(12L * 2304 * 768 * 2);
    short* woT   = (short*)alc(12L * 768 * 768 * 2);
    short* w1T   = (short*)alc(12L * 3072 * 768 * 2);
    short* w2T   = (short*)alc(12L * 768 * 3072 * 2);
    short* convT = (short*)alc(768L * 768 * 2);
    short* cqkvT = (short*)alc(2304L * 768 * 2);
    short* coT   = (short*)alc(768L * 768 * 2);
    short* fh1T  = (short*)alc(384L * 768 * 2);
    short* vh1T  = (short*)alc(384L * 768 * 2);
    short* ch1T  = (short*)alc(384L * 768 * 2);
    short* dummy = (short*)d_ws;

    // ---- weight prep (bf16 transposed [N,K]) ----
    wtrans<<<dim3(24, 24, 12), 256, 0, stream>>>(wq, 589824L, 768, 768, wqkvT, 1769472L, 0);
    wtrans<<<dim3(24, 24, 12), 256, 0, stream>>>(wk, 589824L, 768, 768, wqkvT, 1769472L, 768);
    wtrans<<<dim3(24, 24, 12), 256, 0, stream>>>(wv, 589824L, 768, 768, wqkvT, 1769472L, 1536);
    wtrans<<<dim3(24, 24, 12), 256, 0, stream>>>(wo, 589824L, 768, 768, woT, 589824L, 0);
    wtrans<<<dim3(24, 96, 12), 256, 0, stream>>>(w1, 2359296L, 768, 3072, w1T, 2359296L, 0);
    wtrans<<<dim3(96, 24, 12), 256, 0, stream>>>(w2, 2359296L, 3072, 768, w2T, 2359296L, 0);
    wtrans<<<dim3(24, 24, 1), 256, 0, stream>>>(cwq, 0, 768, 768, cqkvT, 0, 0);
    wtrans<<<dim3(24, 24, 1), 256, 0, stream>>>(cwk, 0, 768, 768, cqkvT, 0, 768);
    wtrans<<<dim3(24, 24, 1), 256, 0, stream>>>(cwv, 0, 768, 768, cqkvT, 0, 1536);
    wtrans<<<dim3(24, 24, 1), 256, 0, stream>>>(cwo, 0, 768, 768, coT, 0, 0);
    wtrans<<<dim3(24, 12, 1), 256, 0, stream>>>(fh_w1, 0, 768, 384, fh1T, 0, 0);
    wtrans<<<dim3(24, 12, 1), 256, 0, stream>>>(vh_w1, 0, 768, 384, vh1T, 0, 0);
    wtrans<<<dim3(24, 12, 1), 256, 0, stream>>>(ch_w1, 0, 768, 384, ch1T, 0, 0);
    f2b_k<<<2304, 256, 0, stream>>>(conv_w, convT, 589824L);

    // ---- patch embedding ----
    patch_gather<<<13056, 256, 0, stream>>>(x, abuf);
    gemm_bt<64, EPI_PATCH><<<dim3(34, 12), 256, 0, stream>>>(
        abuf, 768, convT, 768, 768,
        dummy, 768, conv_b, nullptr, nullptr, h, pos_emb, nullptr, nullptr);
    cls_fix<<<12, 256, 0, stream>>>(cls_tok, pos_emb, h);

    // ---- transformer blocks ----
    for (int l = 0; l < 12; l++) {
        ln_k<<<1088, 256, 0, stream>>>(h, ln1g + l * 768, ln1b + l * 768, abuf);
        gemm_bt<128, EPI_QKV><<<dim3(34, 18), 256, 0, stream>>>(
            abuf, 768, wqkvT + (long)l * 2304 * 768, 768, 768,
            qb, 768, bq + l * 768, bk + l * 768, bv + l * 768,
            nullptr, nullptr, kb, vb);
        vtrans<<<dim3(17, 48), 256, 0, stream>>>(vb, vt);
        flash_attn<<<dim3(17, 48), 256, 0, stream>>>(qb, kb, vt, ctx);
        gemm_bt<64, EPI_RES><<<dim3(34, 12), 256, 0, stream>>>(
            ctx, 768, woT + (long)l * 768 * 768, 768, 768,
            dummy, 768, bo + l * 768, nullptr, nullptr, h, nullptr, nullptr, nullptr);
        ln_k<<<1088, 256, 0, stream>>>(h, ln2g + l * 768, ln2b + l * 768, abuf);
        gemm_bt<128, EPI_GELU><<<dim3(34, 24), 256, 0, stream>>>(
            abuf, 768, w1T + (long)l * 3072 * 768, 768, 768,
            gbuf, 3072, b1 + l * 3072, nullptr, nullptr, nullptr, nullptr, nullptr, nullptr);
        gemm_bt<64, EPI_RES><<<dim3(34, 12), 256, 0, stream>>>(
            gbuf, 3072, w2T + (long)l * 768 * 3072, 3072, 3072,
            dummy, 768, b2 + l * 768, nullptr, nullptr, h, nullptr, nullptr, nullptr);
    }

    // ---- cross-attention ----
    f2b_k<<<13056, 256, 0, stream>>>(h, fbuf, 4352L * 768);
    gemm_bt<128, EPI_QKV><<<dim3(34, 18), 256, 0, stream>>>(
        fbuf, 768, cqkvT, 768, 768,
        qb, 768, cbq, cbk, cbv, nullptr, nullptr, kb, vb);
    vtrans<<<dim3(17, 48), 256, 0, stream>>>(vb, vt);
    flash_attn<<<dim3(17, 48), 256, 0, stream>>>(qb, kb, vt, ctx);
    gemm_bt<64, EPI_BIAS><<<dim3(34, 12), 256, 0, stream>>>(
        ctx, 768, coT, 768, 768,
        vfbuf, 768, cbo, nullptr, nullptr, nullptr, nullptr, nullptr, nullptr);

    // ---- heads ----
    gemm_bt<64, EPI_GELU><<<dim3(34, 6), 256, 0, stream>>>(
        fbuf, 768, fh1T, 768, 768,
        hid, 384, fh_b1, nullptr, nullptr, nullptr, nullptr, nullptr, nullptr);
    logits_k<<<1025, 256, 0, stream>>>(hid, fh_w2, fh_b2, out + 0, 2);
    gemm_bt<64, EPI_GELU><<<dim3(34, 6), 256, 0, stream>>>(
        vfbuf, 768, vh1T, 768, 768,
        hid, 384, vh_b1, nullptr, nullptr, nullptr, nullptr, nullptr, nullptr);
    logits_k<<<1025, 256, 0, stream>>>(hid, vh_w2, vh_b2, out + 8200, 4);
    gemm_bt<64, EPI_GELU><<<dim3(34, 6), 256, 0, stream>>>(
        vfbuf, 768, ch1T, 768, 768,
        hid, 384, ch_b1, nullptr, nullptr, nullptr, nullptr, nullptr, nullptr);
    logits_k<<<1025, 256, 0, stream>>>(hid, ch_w2, ch_b2, out + 24600, 3);

    feats_out<<<3075, 256, 0, stream>>>(h, out + 36900);

    (void)in_sizes; (void)n_in; (void)out_size; (void)ws_size;
}

// Round 4
// 3314.132 us; speedup vs baseline: 1.0530x; 1.0195x over previous
//
#include <hip/hip_runtime.h>

// ============================================================
// CustomUltrasoundViT: 12-layer ViT (B=4, S=1025->pad 1088=17*64, D=768, H=12,
// HD=64, MLP=3072) + cross-attn + 3 heads. bf16 MFMA GEMMs, fp32 residual.
// R4: pad 1088; operand-swapped MFMA -> vectorized epilogues; wave logits.
// R5: XOR bank-swizzle on all MFMA LDS tiles; no mid-iter barrier in flash;
// exp2-domain softmax; row-sum l via ones-column MFMA.
// R6 (REVERTED): cvt_pk/defer-max softmax broke numerics (absmax 0.375).
// R7: flash reverted to R5-exact. (a) V-transpose folded into EPI_QKV
// epilogue (writes vt directly; kills 13 vtrans dispatches + vb buffer);
// (b) EPI_RESB: layer-11 W2 GEMM writes fp32 h AND bf16 fbuf (kills the
// 13056-block f2b_k cast).
// ============================================================

#define SP 1088   // padded sequence length (17*64)

typedef __attribute__((ext_vector_type(8))) short short8;
typedef __attribute__((ext_vector_type(4))) short s16x4;
typedef __attribute__((ext_vector_type(4))) float floatx4;

#define EPI_BF16  0
#define EPI_BIAS  1
#define EPI_QKV   2
#define EPI_RES   3
#define EPI_GELU  4
#define EPI_PATCH 5
#define EPI_RESB  6

// 0.125 (1/sqrt(64)) * log2(e): Q pre-scale so softmax runs in exp2 domain
#define QSCALE 0.18033688011112042f

__device__ __forceinline__ short f2bf(float f) {
    union { float f; unsigned u; } x; x.f = f;
    return (short)((x.u + 0x7fffu + ((x.u >> 16) & 1u)) >> 16);
}
__device__ __forceinline__ float bf2f(short s) {
    union { unsigned u; float f; } x; x.u = ((unsigned)(unsigned short)s) << 16;
    return x.f;
}
__device__ __forceinline__ float gelu_f(float x) {
    return 0.5f * x * (1.f + erff(x * 0.70710678118654752f));
}
__device__ __forceinline__ void gload_lds16(const void* g, void* l) {
    __builtin_amdgcn_global_load_lds((const __attribute__((address_space(1))) void*)g,
                                     (__attribute__((address_space(3))) void*)l, 16, 0, 0);
}

// ------------------------------------------------------------
// gemm_bt: C[M,N] = A[M,K] @ BT[N,K]^T (row-major bf16-as-short).
// BM=128. K-loop: global->VGPR prefetch (2 tiles deep, survives barriers) ->
// swizzled ds_write -> single barrier -> swizzled ds_read frags -> MFMA.
// LDS slot swizzle: slot ^= (row>>1)&3  (8-short slots within 32-short rows)
// -> conflict-free b128 reads (was 4-way: row stride 64B).
// ------------------------------------------------------------
template<int BN, int EPI>
__global__ __launch_bounds__(256)
void gemm_bt(const short* __restrict__ A, int lda,
             const short* __restrict__ Bt, int ldb, int K,
             short* __restrict__ O, int ldo,
             const float* __restrict__ bias0, const float* __restrict__ bias1,
             const float* __restrict__ bias2, float* __restrict__ hres,
             const float* __restrict__ pos,
             short* __restrict__ kout, short* __restrict__ vout)
{
    constexpr int BCH = BN / 64;                 // B-tile 16B chunks per thread
    constexpr int WNS = (BN == 128) ? 64 : 32;   // wave N span
    constexpr int NJ  = WNS / 16;
    __shared__ __align__(16) short As[2][128 * 32];
    __shared__ __align__(16) short Bs[2][BN * 32];

    const int tid = threadIdx.x;
    const int m0 = blockIdx.x * 128, n0 = blockIdx.y * BN;
    const int wave = tid >> 6, lane = tid & 63;
    const int quad = lane >> 4, l15 = lane & 15;
    const int wm = wave >> 1, wn = wave & 1;
    const int srow = tid >> 2, scol = (tid & 3) * 8;
    const int sslot8 = ((tid & 3) ^ ((srow >> 1) & 3)) * 8;   // swizzled LDS write slot
    const int rsw = (l15 >> 1) & 3;                            // read-side swizzle

    const short* Ag = A + (long)(m0 + srow) * lda + scol;
    const short* Bg = Bt + (long)(n0 + srow) * ldb + scol;

    const int NIT = K >> 5;                      // always even, >= 12
    short8 ra[2][2], rb[2][BCH];
    #pragma unroll
    for (int pp = 0; pp < 2; pp++) {
        #pragma unroll
        for (int c = 0; c < 2; c++)
            ra[pp][c] = *(const short8*)(Ag + (long)(64 * c) * lda + pp * 32);
        #pragma unroll
        for (int c = 0; c < BCH; c++)
            rb[pp][c] = *(const short8*)(Bg + (long)(64 * c) * ldb + pp * 32);
    }

    floatx4 acc[4][NJ];
    #pragma unroll
    for (int i = 0; i < 4; i++)
        #pragma unroll
        for (int j = 0; j < NJ; j++)
            acc[i][j] = floatx4{0.f, 0.f, 0.f, 0.f};

    auto step = [&](int it, int pp) {
        short* as = As[pp];
        short* bs = Bs[pp];
        // regs -> LDS (tile it), swizzled slot
        #pragma unroll
        for (int c = 0; c < 2; c++)
            *(short8*)&as[(srow + 64 * c) * 32 + sslot8] = ra[pp][c];
        #pragma unroll
        for (int c = 0; c < BCH; c++)
            *(short8*)&bs[(srow + 64 * c) * 32 + sslot8] = rb[pp][c];
        __syncthreads();
        // issue global loads for tile it+2 (private regs: not drained by barriers)
        if (it + 2 < NIT) {
            const int k0 = (it + 2) * 32;
            #pragma unroll
            for (int c = 0; c < 2; c++)
                ra[pp][c] = *(const short8*)(Ag + (long)(64 * c) * lda + k0);
            #pragma unroll
            for (int c = 0; c < BCH; c++)
                rb[pp][c] = *(const short8*)(Bg + (long)(64 * c) * ldb + k0);
        }
        // LDS -> frags -> MFMA (swapped operands: acc holds C^T fragments)
        short8 af[4], bfrag[NJ];
        #pragma unroll
        for (int i = 0; i < 4; i++)
            af[i] = *(const short8*)&as[(wm * 64 + i * 16 + l15) * 32 + (quad ^ rsw) * 8];
        #pragma unroll
        for (int j = 0; j < NJ; j++)
            bfrag[j] = *(const short8*)&bs[(wn * WNS + j * 16 + l15) * 32 + (quad ^ rsw) * 8];
        #pragma unroll
        for (int i = 0; i < 4; i++)
            #pragma unroll
            for (int j = 0; j < NJ; j++)
                acc[i][j] = __builtin_amdgcn_mfma_f32_16x16x32_bf16(bfrag[j], af[i], acc[i][j], 0, 0, 0);
        // no trailing barrier: next iter writes the other LDS buffer
    };

    #pragma unroll 1
    for (int it = 0; it < NIT; it += 2) {
        step(it, 0);
        step(it + 1, 1);
    }

    // epilogue: thread (quad,l15) holds C[m = .. + l15][n = .. + quad*4 + r]
    const int mb = m0 + wm * 64 + l15;
    const int nbase = n0 + wn * WNS + quad * 4;
    #pragma unroll
    for (int i = 0; i < 4; i++) {
        const int m = mb + i * 16;
        #pragma unroll
        for (int j = 0; j < NJ; j++) {
            const int n = nbase + j * 16;
            floatx4 c4 = acc[i][j];
            if constexpr (EPI == EPI_BF16) {
                s16x4 s;
                #pragma unroll
                for (int r = 0; r < 4; r++) s[r] = f2bf(c4[r]);
                *(s16x4*)(O + (long)m * ldo + n) = s;
            } else if constexpr (EPI == EPI_BIAS) {
                floatx4 bv = *(const floatx4*)(bias0 + n);
                s16x4 s;
                #pragma unroll
                for (int r = 0; r < 4; r++) s[r] = f2bf(c4[r] + bv[r]);
                *(s16x4*)(O + (long)m * ldo + n) = s;
            } else if constexpr (EPI == EPI_QKV) {
                if (n < 768) {
                    floatx4 bv = *(const floatx4*)(bias0 + n);
                    s16x4 s;
                    #pragma unroll
                    for (int r = 0; r < 4; r++) s[r] = f2bf((c4[r] + bv[r]) * QSCALE);
                    *(s16x4*)(O + (long)m * 768 + n) = s;
                } else if (n < 1536) {
                    floatx4 bv = *(const floatx4*)(bias1 + (n - 768));
                    s16x4 s;
                    #pragma unroll
                    for (int r = 0; r < 4; r++) s[r] = f2bf(c4[r] + bv[r]);
                    *(s16x4*)(kout + (long)m * 768 + (n - 768)) = s;
                } else {
                    // V: write transposed directly into vt[(bh*64+d)*SP + s]
                    const int dfull = n - 1536;            // n%4==0 so d..d+3 same head
                    const int hh2 = dfull >> 6, dd = dfull & 63;
                    const int b2 = m / SP, s2 = m - b2 * SP;
                    floatx4 bv = *(const floatx4*)(bias2 + dfull);
                    long vrow = ((long)((b2 * 12 + hh2) * 64 + dd)) * SP + s2;
                    #pragma unroll
                    for (int r = 0; r < 4; r++)
                        vout[vrow + (long)r * SP] = f2bf(c4[r] + bv[r]);
                }
            } else if constexpr (EPI == EPI_RES) {
                floatx4 bv = *(const floatx4*)(bias0 + n);
                floatx4* hp = (floatx4*)(hres + (long)m * 768 + n);
                floatx4 hv = *hp;
                #pragma unroll
                for (int r = 0; r < 4; r++) hv[r] += c4[r] + bv[r];
                *hp = hv;
            } else if constexpr (EPI == EPI_RESB) {
                floatx4 bv = *(const floatx4*)(bias0 + n);
                floatx4* hp = (floatx4*)(hres + (long)m * 768 + n);
                floatx4 hv = *hp;
                #pragma unroll
                for (int r = 0; r < 4; r++) hv[r] += c4[r] + bv[r];
                *hp = hv;
                s16x4 s;
                #pragma unroll
                for (int r = 0; r < 4; r++) s[r] = f2bf(hv[r]);
                *(s16x4*)(O + (long)m * ldo + n) = s;
            } else if constexpr (EPI == EPI_GELU) {
                floatx4 bv = *(const floatx4*)(bias0 + n);
                s16x4 s;
                #pragma unroll
                for (int r = 0; r < 4; r++) s[r] = f2bf(gelu_f(c4[r] + bv[r]));
                *(s16x4*)(O + (long)m * ldo + n) = s;
            } else if constexpr (EPI == EPI_PATCH) {
                const int tok = m % SP;
                floatx4 v = floatx4{0.f, 0.f, 0.f, 0.f};
                if (tok >= 1 && tok < 1025) {
                    floatx4 bv = *(const floatx4*)(bias0 + n);
                    floatx4 pv = *(const floatx4*)(pos + (long)tok * 768 + n);
                    #pragma unroll
                    for (int r = 0; r < 4; r++) v[r] = c4[r] + bv[r] + pv[r];
                }
                *(floatx4*)(hres + (long)m * 768 + n) = v;
            }
        }
    }
}

// ------------------------------------------------------------
// flash attention (R5-exact): one block = 64 Q rows of one (b,h); 4 waves x
// 16 rows. Online softmax (exp2 domain; Q pre-scaled 0.125*log2e) over 17
// K-tiles of 64 (mask s >= 1025). K/V LDS bank-swizzled via pre-swizzled
// global source. One barrier per iter; Ps wave-private -> in-wave lgkmcnt(0).
// Row-sum l via ones-column MFMA.
// ------------------------------------------------------------
__global__ __launch_bounds__(256)
void flash_attn(const short* __restrict__ qb, const short* __restrict__ kb,
                const short* __restrict__ vt, short* __restrict__ ctx)
{
    __shared__ __align__(16) short Ks[2][4096];
    __shared__ __align__(16) short Vs[2][4096];
    __shared__ __align__(16) short Ps[4][1280];

    const int tid = threadIdx.x;
    const int wave = tid >> 6, lane = tid & 63;
    const int quad = lane >> 4, l15 = lane & 15;
    const int bh = blockIdx.y, b = bh / 12, hh = bh - b * 12;
    const int q0 = blockIdx.x * 64;

    const long krow0 = (long)(b * SP) * 768 + hh * 64;
    const long vrow0 = (long)(bh * 64) * SP;
    const int srow = tid >> 2;
    const int scol8 = (tid & 3) ^ ((srow >> 1) & 3);   // pre-swizzled source slot
    const int rsw = (l15 >> 1) & 3;                     // read-side swizzle

    short8 qa[2];
    {
        const int qrow = b * SP + q0 + wave * 16 + l15;
        const short* qp = qb + (long)qrow * 768 + hh * 64 + quad * 8;
        qa[0] = *(const short8*)qp;
        qa[1] = *(const short8*)(qp + 32);
    }

    // ones-column B-frag for row-sum via MFMA (col 0 only)
    const short ov = (l15 == 0) ? (short)0x3F80 : (short)0;
    const short8 vones = {ov, ov, ov, ov, ov, ov, ov, ov};

    floatx4 acco[4];
    #pragma unroll
    for (int j = 0; j < 4; j++) acco[j] = floatx4{0.f, 0.f, 0.f, 0.f};
    floatx4 accl = floatx4{0.f, 0.f, 0.f, 0.f};
    float m_i[4];
    #pragma unroll
    for (int r = 0; r < 4; r++) m_i[r] = -1e30f;

    auto stage = [&](int kt, int buf) {
        #pragma unroll
        for (int it = 0; it < 2; it++) {
            const short* kg = kb + krow0 + (long)(kt * 64 + srow) * 768 + it * 32 + scol8 * 8;
            gload_lds16(kg, (char*)&Ks[buf][0] + (it * 256 + wave * 64) * 16);
            const short* vg = vt + vrow0 + (long)srow * SP + kt * 64 + it * 32 + scol8 * 8;
            gload_lds16(vg, (char*)&Vs[buf][0] + (it * 256 + wave * 64) * 16);
        }
    };

    stage(0, 0);
    for (int kt = 0; kt < 17; kt++) {
        const int cur = kt & 1;
        __syncthreads();               // staging of tile kt complete (vmcnt drain)
        if (kt + 1 < 17) stage(kt + 1, cur ^ 1);   // in flight until next barrier

        floatx4 accs[4];
        #pragma unroll
        for (int j = 0; j < 4; j++) accs[j] = floatx4{0.f, 0.f, 0.f, 0.f};
        #pragma unroll
        for (int c = 0; c < 2; c++)
            #pragma unroll
            for (int j = 0; j < 4; j++) {
                short8 kf = *(const short8*)&Ks[cur][c * 2048 + (j * 16 + l15) * 32 + (quad ^ rsw) * 8];
                accs[j] = __builtin_amdgcn_mfma_f32_16x16x32_bf16(qa[c], kf, accs[j], 0, 0, 0);
            }
        if (kt == 16) {
            #pragma unroll
            for (int j = 0; j < 4; j++)
                if (j != 0 || l15 != 0) {
                    #pragma unroll
                    for (int r = 0; r < 4; r++) accs[j][r] = -1e30f;
                }
        }

        float alpha[4];
        #pragma unroll
        for (int r = 0; r < 4; r++) {
            float mx = fmaxf(fmaxf(accs[0][r], accs[1][r]), fmaxf(accs[2][r], accs[3][r]));
            #pragma unroll
            for (int off = 1; off < 16; off <<= 1) mx = fmaxf(mx, __shfl_xor(mx, off, 64));
            float newm = fmaxf(m_i[r], mx);
            alpha[r] = exp2f(m_i[r] - newm);
            m_i[r] = newm;
        }
        #pragma unroll
        for (int j = 0; j < 4; j++)
            #pragma unroll
            for (int r = 0; r < 4; r++) {
                float p = exp2f(accs[j][r] - m_i[r]);
                Ps[wave][(j >> 1) * 640 + (quad * 4 + r) * 40 + (j & 1) * 16 + l15] = f2bf(p);
            }
        #pragma unroll
        for (int j = 0; j < 4; j++)
            #pragma unroll
            for (int r = 0; r < 4; r++) acco[j][r] *= alpha[r];
        #pragma unroll
        for (int r = 0; r < 4; r++) accl[r] *= alpha[r];

        // Ps is wave-private: in-wave DS ordering only (no block barrier;
        // keeps the stage(kt+1) prefetch in flight through PV)
        asm volatile("s_waitcnt lgkmcnt(0)" ::: "memory");
        __builtin_amdgcn_sched_barrier(0);

        #pragma unroll
        for (int c = 0; c < 2; c++) {
            short8 pa = *(const short8*)&Ps[wave][c * 640 + l15 * 40 + quad * 8];
            #pragma unroll
            for (int j = 0; j < 4; j++) {
                short8 vf = *(const short8*)&Vs[cur][c * 2048 + (j * 16 + l15) * 32 + (quad ^ rsw) * 8];
                acco[j] = __builtin_amdgcn_mfma_f32_16x16x32_bf16(pa, vf, acco[j], 0, 0, 0);
            }
            accl = __builtin_amdgcn_mfma_f32_16x16x32_bf16(pa, vones, accl, 0, 0, 0);
        }
    }

    const int orow = b * SP + q0 + wave * 16 + quad * 4;
    #pragma unroll
    for (int r = 0; r < 4; r++) {
        float lsum = __shfl(accl[r], (lane & 48), 64);   // l lives at l15==0 of same quad
        float inv = 1.f / lsum;
        #pragma unroll
        for (int j = 0; j < 4; j++)
            ctx[(long)(orow + r) * 768 + hh * 64 + j * 16 + l15] = f2bf(acco[j][r] * inv);
    }
}

// ------------------------------------------------------------
__global__ void wtrans(const float* __restrict__ in, long inls, int K, int N,
                       short* __restrict__ out, long outls, int rowoff)
{
    in  += (long)blockIdx.z * inls;
    out += (long)blockIdx.z * outls;
    const int k0 = blockIdx.x * 32, n0 = blockIdx.y * 32;
    const int tx = threadIdx.x & 31, ty = threadIdx.x >> 5;
    __shared__ float t[32][33];
    #pragma unroll
    for (int i = 0; i < 4; i++)
        t[ty + i * 8][tx] = in[(long)(k0 + ty + i * 8) * N + n0 + tx];
    __syncthreads();
    #pragma unroll
    for (int i = 0; i < 4; i++)
        out[(long)(rowoff + n0 + ty + i * 8) * K + k0 + tx] = f2bf(t[tx][ty + i * 8]);
}

__global__ void f2b_k(const float* __restrict__ in, short* __restrict__ out, long n)
{
    long gid = (long)blockIdx.x * 256 + threadIdx.x;
    if (gid < n) out[gid] = f2bf(in[gid]);
}

__global__ void patch_gather(const float* __restrict__ x, short* __restrict__ out)
{
    long gid = (long)blockIdx.x * 256 + threadIdx.x;
    int m = (int)(gid / 768), k = (int)(gid % 768);
    int b = m / SP, tok = m - b * SP;
    short v = 0;
    if (tok >= 1 && tok < 1025) {
        int pidx = tok - 1, py = pidx >> 5, px = pidx & 31;
        int c = k >> 8, rem = k & 255, ii = rem >> 4, jj = rem & 15;
        float f = x[((long)(b * 3 + c) * 512 + py * 16 + ii) * 512 + px * 16 + jj];
        v = f2bf(f);
    }
    out[gid] = v;
}

__global__ void cls_fix(const float* __restrict__ cls, const float* __restrict__ pos,
                        float* __restrict__ h)
{
    int t = blockIdx.x * 256 + threadIdx.x;
    if (t >= 4 * 768) return;
    int b = t / 768, d = t % 768;
    h[(long)b * SP * 768 + d] = cls[d] + pos[d];
}

__global__ void ln_k(const float* __restrict__ h, const float* __restrict__ g,
                     const float* __restrict__ bta, short* __restrict__ out)
{
    int row = blockIdx.x * 4 + (threadIdx.x >> 6);
    int lane = threadIdx.x & 63;
    const float* hr = h + (long)row * 768;
    float v[12], s = 0.f;
    #pragma unroll
    for (int i = 0; i < 12; i++) { v[i] = hr[i * 64 + lane]; s += v[i]; }
    #pragma unroll
    for (int o = 32; o > 0; o >>= 1) s += __shfl_xor(s, o, 64);
    float mean = s * (1.f / 768.f);
    float ss = 0.f;
    #pragma unroll
    for (int i = 0; i < 12; i++) { float d = v[i] - mean; ss += d * d; }
    #pragma unroll
    for (int o = 32; o > 0; o >>= 1) ss += __shfl_xor(ss, o, 64);
    float rstd = rsqrtf(ss * (1.f / 768.f) + 1e-5f);
    #pragma unroll
    for (int i = 0; i < 12; i++) {
        int col = i * 64 + lane;
        out[(long)row * 768 + col] = f2bf((v[i] - mean) * rstd * g[col] + bta[col]);
    }
}

// wave-per-row logits: 4 waves/block, lane-parallel over K=384, shfl reduce.
__global__ void logits_k(const short* __restrict__ hid, const float* __restrict__ w2,
                         const float* __restrict__ b2, float* __restrict__ o, int NO)
{
    int row = blockIdx.x * 4 + (threadIdx.x >> 6);   // 0..4099 (grid 1025)
    int lane = threadIdx.x & 63;
    int b = row / 1025, s = row - b * 1025;
    const short* hr = hid + (long)(b * SP + s) * 384;
    float v[6];
    #pragma unroll
    for (int i = 0; i < 6; i++) v[i] = bf2f(hr[i * 64 + lane]);
    for (int n = 0; n < NO; n++) {
        float a = 0.f;
        #pragma unroll
        for (int i = 0; i < 6; i++) a += v[i] * w2[(i * 64 + lane) * NO + n];
        #pragma unroll
        for (int off = 32; off > 0; off >>= 1) a += __shfl_xor(a, off, 64);
        if (lane == 0) o[row * NO + n] = a + b2[n];
    }
}

__global__ void feats_out(const float* __restrict__ h, float* __restrict__ o)
{
    int gid = blockIdx.x * 256 + threadIdx.x;
    if (gid >= 4 * 1025 * 192) return;
    int row = gid / 192, c4 = gid % 192;
    int b = row / 1025, s = row % 1025;
    const float4* src = (const float4*)(h + (long)(b * SP + s) * 768) + c4;
    float4* dst = (float4*)(o + (long)row * 768) + c4;
    *dst = *src;
}

// ============================================================
extern "C" void kernel_launch(void* const* d_in, const int* in_sizes, int n_in,
                              void* d_out, int out_size, void* d_ws, size_t ws_size,
                              hipStream_t stream)
{
    const float* x       = (const float*)d_in[0];
    const float* conv_w  = (const float*)d_in[1];
    const float* conv_b  = (const float*)d_in[2];
    const float* cls_tok = (const float*)d_in[3];
    const float* pos_emb = (const float*)d_in[4];
    const float* ln1g = (const float*)d_in[5];
    const float* ln1b = (const float*)d_in[6];
    const float* wq = (const float*)d_in[7];
    const float* bq = (const float*)d_in[8];
    const float* wk = (const float*)d_in[9];
    const float* bk = (const float*)d_in[10];
    const float* wv = (const float*)d_in[11];
    const float* bv = (const float*)d_in[12];
    const float* wo = (const float*)d_in[13];
    const float* bo = (const float*)d_in[14];
    const float* ln2g = (const float*)d_in[15];
    const float* ln2b = (const float*)d_in[16];
    const float* w1 = (const float*)d_in[17];
    const float* b1 = (const float*)d_in[18];
    const float* w2 = (const float*)d_in[19];
    const float* b2 = (const float*)d_in[20];
    const float* cwq = (const float*)d_in[21];
    const float* cbq = (const float*)d_in[22];
    const float* cwk = (const float*)d_in[23];
    const float* cbk = (const float*)d_in[24];
    const float* cwv = (const float*)d_in[25];
    const float* cbv = (const float*)d_in[26];
    const float* cwo = (const float*)d_in[27];
    const float* cbo = (const float*)d_in[28];
    const float* fh_w1 = (const float*)d_in[29];
    const float* fh_b1 = (const float*)d_in[30];
    const float* fh_w2 = (const float*)d_in[31];
    const float* fh_b2 = (const float*)d_in[32];
    const float* vh_w1 = (const float*)d_in[33];
    const float* vh_b1 = (const float*)d_in[34];
    const float* vh_w2 = (const float*)d_in[35];
    const float* vh_b2 = (const float*)d_in[36];
    const float* ch_w1 = (const float*)d_in[37];
    const float* ch_b1 = (const float*)d_in[38];
    const float* ch_w2 = (const float*)d_in[39];
    const float* ch_b2 = (const float*)d_in[40];
    float* out = (float*)d_out;

    // ---- workspace carve-up (M = 4*SP = 4352 rows) ----
    char* ws = (char*)d_ws;
    size_t off = 0;
    auto alc = [&](size_t b) { char* p = ws + off; off += (b + 255) & ~(size_t)255; return p; };
    float* h     = (float*)alc(4352L * 768 * 4);
    short* abuf  = (short*)alc(4352L * 768 * 2);
    short* gbuf  = (short*)alc(4352L * 3072 * 2);
    short* qb    = (short*)alc(4352L * 768 * 2);
    short* kb    = (short*)alc(4352L * 768 * 2);
    short* vt    = (short*)alc(48L * 64 * SP * 2);
    short* ctx   = (short*)alc(4352L * 768 * 2);
    short* fbuf  = (short*)alc(4352L * 768 * 2);
    short* vfbuf = (short*)alc(4352L * 768 * 2);
    short* hid   = (short*)alc(4352L * 384 * 2);
    short* wqkvT = (short*)alc(12L * 2304 * 768 * 2);
    short* woT   = (short*)alc(12L * 768 * 768 * 2);
    short* w1T   = (short*)alc(12L * 3072 * 768 * 2);
    short* w2T   = (short*)alc(12L * 768 * 3072 * 2);
    short* convT = (short*)alc(768L * 768 * 2);
    short* cqkvT = (short*)alc(2304L * 768 * 2);
    short* coT   = (short*)alc(768L * 768 * 2);
    short* fh1T  = (short*)alc(384L * 768 * 2);
    short* vh1T  = (short*)alc(384L * 768 * 2);
    short* ch1T  = (short*)alc(384L * 768 * 2);
    short* dummy = (short*)d_ws;

    // ---- weight prep (bf16 transposed [N,K]) ----
    wtrans<<<dim3(24, 24, 12), 256, 0, stream>>>(wq, 589824L, 768, 768, wqkvT, 1769472L, 0);
    wtrans<<<dim3(24, 24, 12), 256, 0, stream>>>(wk, 589824L, 768, 768, wqkvT, 1769472L, 768);
    wtrans<<<dim3(24, 24, 12), 256, 0, stream>>>(wv, 589824L, 768, 768, wqkvT, 1769472L, 1536);
    wtrans<<<dim3(24, 24, 12), 256, 0, stream>>>(wo, 589824L, 768, 768, woT, 589824L, 0);
    wtrans<<<dim3(24, 96, 12), 256, 0, stream>>>(w1, 2359296L, 768, 3072, w1T, 2359296L, 0);
    wtrans<<<dim3(96, 24, 12), 256, 0, stream>>>(w2, 2359296L, 3072, 768, w2T, 2359296L, 0);
    wtrans<<<dim3(24, 24, 1), 256, 0, stream>>>(cwq, 0, 768, 768, cqkvT, 0, 0);
    wtrans<<<dim3(24, 24, 1), 256, 0, stream>>>(cwk, 0, 768, 768, cqkvT, 0, 768);
    wtrans<<<dim3(24, 24, 1), 256, 0, stream>>>(cwv, 0, 768, 768, cqkvT, 0, 1536);
    wtrans<<<dim3(24, 24, 1), 256, 0, stream>>>(cwo, 0, 768, 768, coT, 0, 0);
    wtrans<<<dim3(24, 12, 1), 256, 0, stream>>>(fh_w1, 0, 768, 384, fh1T, 0, 0);
    wtrans<<<dim3(24, 12, 1), 256, 0, stream>>>(vh_w1, 0, 768, 384, vh1T, 0, 0);
    wtrans<<<dim3(24, 12, 1), 256, 0, stream>>>(ch_w1, 0, 768, 384, ch1T, 0, 0);
    f2b_k<<<2304, 256, 0, stream>>>(conv_w, convT, 589824L);

    // ---- patch embedding ----
    patch_gather<<<13056, 256, 0, stream>>>(x, abuf);
    gemm_bt<64, EPI_PATCH><<<dim3(34, 12), 256, 0, stream>>>(
        abuf, 768, convT, 768, 768,
        dummy, 768, conv_b, nullptr, nullptr, h, pos_emb, nullptr, nullptr);
    cls_fix<<<12, 256, 0, stream>>>(cls_tok, pos_emb, h);

    // ---- transformer blocks ----
    for (int l = 0; l < 12; l++) {
        ln_k<<<1088, 256, 0, stream>>>(h, ln1g + l * 768, ln1b + l * 768, abuf);
        gemm_bt<128, EPI_QKV><<<dim3(34, 18), 256, 0, stream>>>(
            abuf, 768, wqkvT + (long)l * 2304 * 768, 768, 768,
            qb, 768, bq + l * 768, bk + l * 768, bv + l * 768,
            nullptr, nullptr, kb, vt);
        flash_attn<<<dim3(17, 48), 256, 0, stream>>>(qb, kb, vt, ctx);
        gemm_bt<64, EPI_RES><<<dim3(34, 12), 256, 0, stream>>>(
            ctx, 768, woT + (long)l * 768 * 768, 768, 768,
            dummy, 768, bo + l * 768, nullptr, nullptr, h, nullptr, nullptr, nullptr);
        ln_k<<<1088, 256, 0, stream>>>(h, ln2g + l * 768, ln2b + l * 768, abuf);
        gemm_bt<128, EPI_GELU><<<dim3(34, 24), 256, 0, stream>>>(
            abuf, 768, w1T + (long)l * 3072 * 768, 768, 768,
            gbuf, 3072, b1 + l * 3072, nullptr, nullptr, nullptr, nullptr, nullptr, nullptr);
        if (l < 11) {
            gemm_bt<64, EPI_RES><<<dim3(34, 12), 256, 0, stream>>>(
                gbuf, 3072, w2T + (long)l * 768 * 3072, 3072, 3072,
                dummy, 768, b2 + l * 768, nullptr, nullptr, h, nullptr, nullptr, nullptr);
        } else {
            // final residual: also emit bf16 copy of h into fbuf
            gemm_bt<64, EPI_RESB><<<dim3(34, 12), 256, 0, stream>>>(
                gbuf, 3072, w2T + (long)l * 768 * 3072, 3072, 3072,
                fbuf, 768, b2 + l * 768, nullptr, nullptr, h, nullptr, nullptr, nullptr);
        }
    }

    // ---- cross-attention ----
    gemm_bt<128, EPI_QKV><<<dim3(34, 18), 256, 0, stream>>>(
        fbuf, 768, cqkvT, 768, 768,
        qb, 768, cbq, cbk, cbv, nullptr, nullptr, kb, vt);
    flash_attn<<<dim3(17, 48), 256, 0, stream>>>(qb, kb, vt, ctx);
    gemm_bt<64, EPI_BIAS><<<dim3(34, 12), 256, 0, stream>>>(
        ctx, 768, coT, 768, 768,
        vfbuf, 768, cbo, nullptr, nullptr, nullptr, nullptr, nullptr, nullptr);

    // ---- heads ----
    gemm_bt<64, EPI_GELU><<<dim3(34, 6), 256, 0, stream>>>(
        fbuf, 768, fh1T, 768, 768,
        hid, 384, fh_b1, nullptr, nullptr, nullptr, nullptr, nullptr, nullptr);
    logits_k<<<1025, 256, 0, stream>>>(hid, fh_w2, fh_b2, out + 0, 2);
    gemm_bt<64, EPI_GELU><<<dim3(34, 6), 256, 0, stream>>>(
        vfbuf, 768, vh1T, 768, 768,
        hid, 384, vh_b1, nullptr, nullptr, nullptr, nullptr, nullptr, nullptr);
    logits_k<<<1025, 256, 0, stream>>>(hid, vh_w2, vh_b2, out + 8200, 4);
    gemm_bt<64, EPI_GELU><<<dim3(34, 6), 256, 0, stream>>>(
        vfbuf, 768, ch1T, 768, 768,
        hid, 384, ch_b1, nullptr, nullptr, nullptr, nullptr, nullptr, nullptr);
    logits_k<<<1025, 256, 0, stream>>>(hid, ch_w2, ch_b2, out + 24600, 3);

    feats_out<<<3075, 256, 0, stream>>>(h, out + 36900);

    (void)in_sizes; (void)n_in; (void)out_size; (void)ws_size;
}

// Round 5
// 3267.810 us; speedup vs baseline: 1.0679x; 1.0142x over previous
//
#include <hip/hip_runtime.h>

// ============================================================
// CustomUltrasoundViT: 12-layer ViT (B=4, S=1025->pad 1088=17*64, D=768, H=12,
// HD=64, MLP=3072) + cross-attn + 3 heads. bf16 MFMA GEMMs, fp32 residual.
// R4: pad 1088; operand-swapped MFMA -> vectorized epilogues; wave logits.
// R5: XOR bank-swizzle on all MFMA LDS tiles; no mid-iter barrier in flash;
// exp2-domain softmax; row-sum l via ones-column MFMA.
// R7: V-transpose folded into EPI_QKV; EPI_RESB fuses final f2b cast.
// R8: GEMM K-step 32->64 (BK=64): halves barrier count (the 9.5% MfmaUtil
// at zero conflicts + 25% occupancy = barrier-serialization), doubles MFMA
// per phase. Same K-accumulation order -> bit-identical results. Swizzle
// re-derived for 128B rows: write slot (tid&7)^((tid>>3)&7), read slot
// ((c*4+quad)^(l15&7)).
// ============================================================

#define SP 1088   // padded sequence length (17*64)

typedef __attribute__((ext_vector_type(8))) short short8;
typedef __attribute__((ext_vector_type(4))) short s16x4;
typedef __attribute__((ext_vector_type(4))) float floatx4;

#define EPI_BF16  0
#define EPI_BIAS  1
#define EPI_QKV   2
#define EPI_RES   3
#define EPI_GELU  4
#define EPI_PATCH 5
#define EPI_RESB  6

// 0.125 (1/sqrt(64)) * log2(e): Q pre-scale so softmax runs in exp2 domain
#define QSCALE 0.18033688011112042f

__device__ __forceinline__ short f2bf(float f) {
    union { float f; unsigned u; } x; x.f = f;
    return (short)((x.u + 0x7fffu + ((x.u >> 16) & 1u)) >> 16);
}
__device__ __forceinline__ float bf2f(short s) {
    union { unsigned u; float f; } x; x.u = ((unsigned)(unsigned short)s) << 16;
    return x.f;
}
__device__ __forceinline__ float gelu_f(float x) {
    return 0.5f * x * (1.f + erff(x * 0.70710678118654752f));
}
__device__ __forceinline__ void gload_lds16(const void* g, void* l) {
    __builtin_amdgcn_global_load_lds((const __attribute__((address_space(1))) void*)g,
                                     (__attribute__((address_space(3))) void*)l, 16, 0, 0);
}

// ------------------------------------------------------------
// gemm_bt: C[M,N] = A[M,K] @ BT[N,K]^T (row-major bf16-as-short).
// BM=128, BK=64. K-loop: global->VGPR prefetch (2 tiles deep, survives
// barriers) -> swizzled ds_write -> single barrier -> swizzled ds_read
// frags -> 2x16 (BN=128) MFMA. LDS double-buffered.
// 128B LDS rows (64 shorts): 8 slots of 16B; slot ^= row&7.
// ------------------------------------------------------------
template<int BN, int EPI>
__global__ __launch_bounds__(256)
void gemm_bt(const short* __restrict__ A, int lda,
             const short* __restrict__ Bt, int ldb, int K,
             short* __restrict__ O, int ldo,
             const float* __restrict__ bias0, const float* __restrict__ bias1,
             const float* __restrict__ bias2, float* __restrict__ hres,
             const float* __restrict__ pos,
             short* __restrict__ kout, short* __restrict__ vout)
{
    constexpr int ACH = 4;                       // A-tile 16B chunks per thread (128x64/256/8)
    constexpr int BCH = BN / 32;                 // B-tile chunks per thread
    constexpr int WNS = (BN == 128) ? 64 : 32;   // wave N span
    constexpr int NJ  = WNS / 16;
    __shared__ __align__(16) short As[2][128 * 64];
    __shared__ __align__(16) short Bs[2][BN * 64];

    const int tid = threadIdx.x;
    const int m0 = blockIdx.x * 128, n0 = blockIdx.y * BN;
    const int wave = tid >> 6, lane = tid & 63;
    const int quad = lane >> 4, l15 = lane & 15;
    const int wm = wave >> 1, wn = wave & 1;
    const int wr = tid >> 3;                     // staging row within 32-row group
    const int wcol = (tid & 7) * 8;              // staging col (shorts)
    const int wslot = ((tid & 7) ^ (wr & 7)) * 8;   // swizzled LDS write slot
    const int sw7 = l15 & 7;                     // read-side swizzle key

    const short* Ag = A + (long)(m0 + wr) * lda + wcol;
    const short* Bg = Bt + (long)(n0 + wr) * ldb + wcol;

    const int NIT = K >> 6;                      // K/64: 12 (K=768) or 48 (K=3072)
    short8 ra[2][ACH], rb[2][BCH];
    #pragma unroll
    for (int pp = 0; pp < 2; pp++) {
        #pragma unroll
        for (int c = 0; c < ACH; c++)
            ra[pp][c] = *(const short8*)(Ag + (long)(32 * c) * lda + pp * 64);
        #pragma unroll
        for (int c = 0; c < BCH; c++)
            rb[pp][c] = *(const short8*)(Bg + (long)(32 * c) * ldb + pp * 64);
    }

    floatx4 acc[4][NJ];
    #pragma unroll
    for (int i = 0; i < 4; i++)
        #pragma unroll
        for (int j = 0; j < NJ; j++)
            acc[i][j] = floatx4{0.f, 0.f, 0.f, 0.f};

    auto step = [&](int it, int pp) {
        short* as = As[pp];
        short* bs = Bs[pp];
        // regs -> LDS (tile it), swizzled slot
        #pragma unroll
        for (int c = 0; c < ACH; c++)
            *(short8*)&as[(c * 32 + wr) * 64 + wslot] = ra[pp][c];
        #pragma unroll
        for (int c = 0; c < BCH; c++)
            *(short8*)&bs[(c * 32 + wr) * 64 + wslot] = rb[pp][c];
        __syncthreads();
        // issue global loads for tile it+2 (private regs: not drained by barriers)
        if (it + 2 < NIT) {
            const int k0 = (it + 2) * 64;
            #pragma unroll
            for (int c = 0; c < ACH; c++)
                ra[pp][c] = *(const short8*)(Ag + (long)(32 * c) * lda + k0);
            #pragma unroll
            for (int c = 0; c < BCH; c++)
                rb[pp][c] = *(const short8*)(Bg + (long)(32 * c) * ldb + k0);
        }
        // LDS -> frags -> MFMA; two K=32 halves (c), same order as two BK=32 steps
        #pragma unroll
        for (int c = 0; c < 2; c++) {
            const int pslot = ((c * 4 + quad) ^ sw7) * 8;
            short8 af[4], bfrag[NJ];
            #pragma unroll
            for (int i = 0; i < 4; i++)
                af[i] = *(const short8*)&as[(wm * 64 + i * 16 + l15) * 64 + pslot];
            #pragma unroll
            for (int j = 0; j < NJ; j++)
                bfrag[j] = *(const short8*)&bs[(wn * WNS + j * 16 + l15) * 64 + pslot];
            #pragma unroll
            for (int i = 0; i < 4; i++)
                #pragma unroll
                for (int j = 0; j < NJ; j++)
                    acc[i][j] = __builtin_amdgcn_mfma_f32_16x16x32_bf16(bfrag[j], af[i], acc[i][j], 0, 0, 0);
        }
        // no trailing barrier: next iter writes the other LDS buffer
    };

    #pragma unroll 1
    for (int it = 0; it < NIT; it += 2) {
        step(it, 0);
        step(it + 1, 1);
    }

    // epilogue: thread (quad,l15) holds C[m = .. + l15][n = .. + quad*4 + r]
    const int mb = m0 + wm * 64 + l15;
    const int nbase = n0 + wn * WNS + quad * 4;
    #pragma unroll
    for (int i = 0; i < 4; i++) {
        const int m = mb + i * 16;
        #pragma unroll
        for (int j = 0; j < NJ; j++) {
            const int n = nbase + j * 16;
            floatx4 c4 = acc[i][j];
            if constexpr (EPI == EPI_BF16) {
                s16x4 s;
                #pragma unroll
                for (int r = 0; r < 4; r++) s[r] = f2bf(c4[r]);
                *(s16x4*)(O + (long)m * ldo + n) = s;
            } else if constexpr (EPI == EPI_BIAS) {
                floatx4 bv = *(const floatx4*)(bias0 + n);
                s16x4 s;
                #pragma unroll
                for (int r = 0; r < 4; r++) s[r] = f2bf(c4[r] + bv[r]);
                *(s16x4*)(O + (long)m * ldo + n) = s;
            } else if constexpr (EPI == EPI_QKV) {
                if (n < 768) {
                    floatx4 bv = *(const floatx4*)(bias0 + n);
                    s16x4 s;
                    #pragma unroll
                    for (int r = 0; r < 4; r++) s[r] = f2bf((c4[r] + bv[r]) * QSCALE);
                    *(s16x4*)(O + (long)m * 768 + n) = s;
                } else if (n < 1536) {
                    floatx4 bv = *(const floatx4*)(bias1 + (n - 768));
                    s16x4 s;
                    #pragma unroll
                    for (int r = 0; r < 4; r++) s[r] = f2bf(c4[r] + bv[r]);
                    *(s16x4*)(kout + (long)m * 768 + (n - 768)) = s;
                } else {
                    // V: write transposed directly into vt[(bh*64+d)*SP + s]
                    const int dfull = n - 1536;            // n%4==0 so d..d+3 same head
                    const int hh2 = dfull >> 6, dd = dfull & 63;
                    const int b2 = m / SP, s2 = m - b2 * SP;
                    floatx4 bv = *(const floatx4*)(bias2 + dfull);
                    long vrow = ((long)((b2 * 12 + hh2) * 64 + dd)) * SP + s2;
                    #pragma unroll
                    for (int r = 0; r < 4; r++)
                        vout[vrow + (long)r * SP] = f2bf(c4[r] + bv[r]);
                }
            } else if constexpr (EPI == EPI_RES) {
                floatx4 bv = *(const floatx4*)(bias0 + n);
                floatx4* hp = (floatx4*)(hres + (long)m * 768 + n);
                floatx4 hv = *hp;
                #pragma unroll
                for (int r = 0; r < 4; r++) hv[r] += c4[r] + bv[r];
                *hp = hv;
            } else if constexpr (EPI == EPI_RESB) {
                floatx4 bv = *(const floatx4*)(bias0 + n);
                floatx4* hp = (floatx4*)(hres + (long)m * 768 + n);
                floatx4 hv = *hp;
                #pragma unroll
                for (int r = 0; r < 4; r++) hv[r] += c4[r] + bv[r];
                *hp = hv;
                s16x4 s;
                #pragma unroll
                for (int r = 0; r < 4; r++) s[r] = f2bf(hv[r]);
                *(s16x4*)(O + (long)m * ldo + n) = s;
            } else if constexpr (EPI == EPI_GELU) {
                floatx4 bv = *(const floatx4*)(bias0 + n);
                s16x4 s;
                #pragma unroll
                for (int r = 0; r < 4; r++) s[r] = f2bf(gelu_f(c4[r] + bv[r]));
                *(s16x4*)(O + (long)m * ldo + n) = s;
            } else if constexpr (EPI == EPI_PATCH) {
                const int tok = m % SP;
                floatx4 v = floatx4{0.f, 0.f, 0.f, 0.f};
                if (tok >= 1 && tok < 1025) {
                    floatx4 bv = *(const floatx4*)(bias0 + n);
                    floatx4 pv = *(const floatx4*)(pos + (long)tok * 768 + n);
                    #pragma unroll
                    for (int r = 0; r < 4; r++) v[r] = c4[r] + bv[r] + pv[r];
                }
                *(floatx4*)(hres + (long)m * 768 + n) = v;
            }
        }
    }
}

// ------------------------------------------------------------
// flash attention (R5-exact): one block = 64 Q rows of one (b,h); 4 waves x
// 16 rows. Online softmax (exp2 domain; Q pre-scaled 0.125*log2e) over 17
// K-tiles of 64 (mask s >= 1025). K/V LDS bank-swizzled via pre-swizzled
// global source. One barrier per iter; Ps wave-private -> in-wave lgkmcnt(0).
// Row-sum l via ones-column MFMA.
// ------------------------------------------------------------
__global__ __launch_bounds__(256)
void flash_attn(const short* __restrict__ qb, const short* __restrict__ kb,
                const short* __restrict__ vt, short* __restrict__ ctx)
{
    __shared__ __align__(16) short Ks[2][4096];
    __shared__ __align__(16) short Vs[2][4096];
    __shared__ __align__(16) short Ps[4][1280];

    const int tid = threadIdx.x;
    const int wave = tid >> 6, lane = tid & 63;
    const int quad = lane >> 4, l15 = lane & 15;
    const int bh = blockIdx.y, b = bh / 12, hh = bh - b * 12;
    const int q0 = blockIdx.x * 64;

    const long krow0 = (long)(b * SP) * 768 + hh * 64;
    const long vrow0 = (long)(bh * 64) * SP;
    const int srow = tid >> 2;
    const int scol8 = (tid & 3) ^ ((srow >> 1) & 3);   // pre-swizzled source slot
    const int rsw = (l15 >> 1) & 3;                     // read-side swizzle

    short8 qa[2];
    {
        const int qrow = b * SP + q0 + wave * 16 + l15;
        const short* qp = qb + (long)qrow * 768 + hh * 64 + quad * 8;
        qa[0] = *(const short8*)qp;
        qa[1] = *(const short8*)(qp + 32);
    }

    // ones-column B-frag for row-sum via MFMA (col 0 only)
    const short ov = (l15 == 0) ? (short)0x3F80 : (short)0;
    const short8 vones = {ov, ov, ov, ov, ov, ov, ov, ov};

    floatx4 acco[4];
    #pragma unroll
    for (int j = 0; j < 4; j++) acco[j] = floatx4{0.f, 0.f, 0.f, 0.f};
    floatx4 accl = floatx4{0.f, 0.f, 0.f, 0.f};
    float m_i[4];
    #pragma unroll
    for (int r = 0; r < 4; r++) m_i[r] = -1e30f;

    auto stage = [&](int kt, int buf) {
        #pragma unroll
        for (int it = 0; it < 2; it++) {
            const short* kg = kb + krow0 + (long)(kt * 64 + srow) * 768 + it * 32 + scol8 * 8;
            gload_lds16(kg, (char*)&Ks[buf][0] + (it * 256 + wave * 64) * 16);
            const short* vg = vt + vrow0 + (long)srow * SP + kt * 64 + it * 32 + scol8 * 8;
            gload_lds16(vg, (char*)&Vs[buf][0] + (it * 256 + wave * 64) * 16);
        }
    };

    stage(0, 0);
    for (int kt = 0; kt < 17; kt++) {
        const int cur = kt & 1;
        __syncthreads();               // staging of tile kt complete (vmcnt drain)
        if (kt + 1 < 17) stage(kt + 1, cur ^ 1);   // in flight until next barrier

        floatx4 accs[4];
        #pragma unroll
        for (int j = 0; j < 4; j++) accs[j] = floatx4{0.f, 0.f, 0.f, 0.f};
        #pragma unroll
        for (int c = 0; c < 2; c++)
            #pragma unroll
            for (int j = 0; j < 4; j++) {
                short8 kf = *(const short8*)&Ks[cur][c * 2048 + (j * 16 + l15) * 32 + (quad ^ rsw) * 8];
                accs[j] = __builtin_amdgcn_mfma_f32_16x16x32_bf16(qa[c], kf, accs[j], 0, 0, 0);
            }
        if (kt == 16) {
            #pragma unroll
            for (int j = 0; j < 4; j++)
                if (j != 0 || l15 != 0) {
                    #pragma unroll
                    for (int r = 0; r < 4; r++) accs[j][r] = -1e30f;
                }
        }

        float alpha[4];
        #pragma unroll
        for (int r = 0; r < 4; r++) {
            float mx = fmaxf(fmaxf(accs[0][r], accs[1][r]), fmaxf(accs[2][r], accs[3][r]));
            #pragma unroll
            for (int off = 1; off < 16; off <<= 1) mx = fmaxf(mx, __shfl_xor(mx, off, 64));
            float newm = fmaxf(m_i[r], mx);
            alpha[r] = exp2f(m_i[r] - newm);
            m_i[r] = newm;
        }
        #pragma unroll
        for (int j = 0; j < 4; j++)
            #pragma unroll
            for (int r = 0; r < 4; r++) {
                float p = exp2f(accs[j][r] - m_i[r]);
                Ps[wave][(j >> 1) * 640 + (quad * 4 + r) * 40 + (j & 1) * 16 + l15] = f2bf(p);
            }
        #pragma unroll
        for (int j = 0; j < 4; j++)
            #pragma unroll
            for (int r = 0; r < 4; r++) acco[j][r] *= alpha[r];
        #pragma unroll
        for (int r = 0; r < 4; r++) accl[r] *= alpha[r];

        // Ps is wave-private: in-wave DS ordering only (no block barrier;
        // keeps the stage(kt+1) prefetch in flight through PV)
        asm volatile("s_waitcnt lgkmcnt(0)" ::: "memory");
        __builtin_amdgcn_sched_barrier(0);

        #pragma unroll
        for (int c = 0; c < 2; c++) {
            short8 pa = *(const short8*)&Ps[wave][c * 640 + l15 * 40 + quad * 8];
            #pragma unroll
            for (int j = 0; j < 4; j++) {
                short8 vf = *(const short8*)&Vs[cur][c * 2048 + (j * 16 + l15) * 32 + (quad ^ rsw) * 8];
                acco[j] = __builtin_amdgcn_mfma_f32_16x16x32_bf16(pa, vf, acco[j], 0, 0, 0);
            }
            accl = __builtin_amdgcn_mfma_f32_16x16x32_bf16(pa, vones, accl, 0, 0, 0);
        }
    }

    const int orow = b * SP + q0 + wave * 16 + quad * 4;
    #pragma unroll
    for (int r = 0; r < 4; r++) {
        float lsum = __shfl(accl[r], (lane & 48), 64);   // l lives at l15==0 of same quad
        float inv = 1.f / lsum;
        #pragma unroll
        for (int j = 0; j < 4; j++)
            ctx[(long)(orow + r) * 768 + hh * 64 + j * 16 + l15] = f2bf(acco[j][r] * inv);
    }
}

// ------------------------------------------------------------
__global__ void wtrans(const float* __restrict__ in, long inls, int K, int N,
                       short* __restrict__ out, long outls, int rowoff)
{
    in  += (long)blockIdx.z * inls;
    out += (long)blockIdx.z * outls;
    const int k0 = blockIdx.x * 32, n0 = blockIdx.y * 32;
    const int tx = threadIdx.x & 31, ty = threadIdx.x >> 5;
    __shared__ float t[32][33];
    #pragma unroll
    for (int i = 0; i < 4; i++)
        t[ty + i * 8][tx] = in[(long)(k0 + ty + i * 8) * N + n0 + tx];
    __syncthreads();
    #pragma unroll
    for (int i = 0; i < 4; i++)
        out[(long)(rowoff + n0 + ty + i * 8) * K + k0 + tx] = f2bf(t[tx][ty + i * 8]);
}

__global__ void f2b_k(const float* __restrict__ in, short* __restrict__ out, long n)
{
    long gid = (long)blockIdx.x * 256 + threadIdx.x;
    if (gid < n) out[gid] = f2bf(in[gid]);
}

__global__ void patch_gather(const float* __restrict__ x, short* __restrict__ out)
{
    long gid = (long)blockIdx.x * 256 + threadIdx.x;
    int m = (int)(gid / 768), k = (int)(gid % 768);
    int b = m / SP, tok = m - b * SP;
    short v = 0;
    if (tok >= 1 && tok < 1025) {
        int pidx = tok - 1, py = pidx >> 5, px = pidx & 31;
        int c = k >> 8, rem = k & 255, ii = rem >> 4, jj = rem & 15;
        float f = x[((long)(b * 3 + c) * 512 + py * 16 + ii) * 512 + px * 16 + jj];
        v = f2bf(f);
    }
    out[gid] = v;
}

__global__ void cls_fix(const float* __restrict__ cls, const float* __restrict__ pos,
                        float* __restrict__ h)
{
    int t = blockIdx.x * 256 + threadIdx.x;
    if (t >= 4 * 768) return;
    int b = t / 768, d = t % 768;
    h[(long)b * SP * 768 + d] = cls[d] + pos[d];
}

__global__ void ln_k(const float* __restrict__ h, const float* __restrict__ g,
                     const float* __restrict__ bta, short* __restrict__ out)
{
    int row = blockIdx.x * 4 + (threadIdx.x >> 6);
    int lane = threadIdx.x & 63;
    const float* hr = h + (long)row * 768;
    float v[12], s = 0.f;
    #pragma unroll
    for (int i = 0; i < 12; i++) { v[i] = hr[i * 64 + lane]; s += v[i]; }
    #pragma unroll
    for (int o = 32; o > 0; o >>= 1) s += __shfl_xor(s, o, 64);
    float mean = s * (1.f / 768.f);
    float ss = 0.f;
    #pragma unroll
    for (int i = 0; i < 12; i++) { float d = v[i] - mean; ss += d * d; }
    #pragma unroll
    for (int o = 32; o > 0; o >>= 1) ss += __shfl_xor(ss, o, 64);
    float rstd = rsqrtf(ss * (1.f / 768.f) + 1e-5f);
    #pragma unroll
    for (int i = 0; i < 12; i++) {
        int col = i * 64 + lane;
        out[(long)row * 768 + col] = f2bf((v[i] - mean) * rstd * g[col] + bta[col]);
    }
}

// wave-per-row logits: 4 waves/block, lane-parallel over K=384, shfl reduce.
__global__ void logits_k(const short* __restrict__ hid, const float* __restrict__ w2,
                         const float* __restrict__ b2, float* __restrict__ o, int NO)
{
    int row = blockIdx.x * 4 + (threadIdx.x >> 6);   // 0..4099 (grid 1025)
    int lane = threadIdx.x & 63;
    int b = row / 1025, s = row - b * 1025;
    const short* hr = hid + (long)(b * SP + s) * 384;
    float v[6];
    #pragma unroll
    for (int i = 0; i < 6; i++) v[i] = bf2f(hr[i * 64 + lane]);
    for (int n = 0; n < NO; n++) {
        float a = 0.f;
        #pragma unroll
        for (int i = 0; i < 6; i++) a += v[i] * w2[(i * 64 + lane) * NO + n];
        #pragma unroll
        for (int off = 32; off > 0; off >>= 1) a += __shfl_xor(a, off, 64);
        if (lane == 0) o[row * NO + n] = a + b2[n];
    }
}

__global__ void feats_out(const float* __restrict__ h, float* __restrict__ o)
{
    int gid = blockIdx.x * 256 + threadIdx.x;
    if (gid >= 4 * 1025 * 192) return;
    int row = gid / 192, c4 = gid % 192;
    int b = row / 1025, s = row % 1025;
    const float4* src = (const float4*)(h + (long)(b * SP + s) * 768) + c4;
    float4* dst = (float4*)(o + (long)row * 768) + c4;
    *dst = *src;
}

// ============================================================
extern "C" void kernel_launch(void* const* d_in, const int* in_sizes, int n_in,
                              void* d_out, int out_size, void* d_ws, size_t ws_size,
                              hipStream_t stream)
{
    const float* x       = (const float*)d_in[0];
    const float* conv_w  = (const float*)d_in[1];
    const float* conv_b  = (const float*)d_in[2];
    const float* cls_tok = (const float*)d_in[3];
    const float* pos_emb = (const float*)d_in[4];
    const float* ln1g = (const float*)d_in[5];
    const float* ln1b = (const float*)d_in[6];
    const float* wq = (const float*)d_in[7];
    const float* bq = (const float*)d_in[8];
    const float* wk = (const float*)d_in[9];
    const float* bk = (const float*)d_in[10];
    const float* wv = (const float*)d_in[11];
    const float* bv = (const float*)d_in[12];
    const float* wo = (const float*)d_in[13];
    const float* bo = (const float*)d_in[14];
    const float* ln2g = (const float*)d_in[15];
    const float* ln2b = (const float*)d_in[16];
    const float* w1 = (const float*)d_in[17];
    const float* b1 = (const float*)d_in[18];
    const float* w2 = (const float*)d_in[19];
    const float* b2 = (const float*)d_in[20];
    const float* cwq = (const float*)d_in[21];
    const float* cbq = (const float*)d_in[22];
    const float* cwk = (const float*)d_in[23];
    const float* cbk = (const float*)d_in[24];
    const float* cwv = (const float*)d_in[25];
    const float* cbv = (const float*)d_in[26];
    const float* cwo = (const float*)d_in[27];
    const float* cbo = (const float*)d_in[28];
    const float* fh_w1 = (const float*)d_in[29];
    const float* fh_b1 = (const float*)d_in[30];
    const float* fh_w2 = (const float*)d_in[31];
    const float* fh_b2 = (const float*)d_in[32];
    const float* vh_w1 = (const float*)d_in[33];
    const float* vh_b1 = (const float*)d_in[34];
    const float* vh_w2 = (const float*)d_in[35];
    const float* vh_b2 = (const float*)d_in[36];
    const float* ch_w1 = (const float*)d_in[37];
    const float* ch_b1 = (const float*)d_in[38];
    const float* ch_w2 = (const float*)d_in[39];
    const float* ch_b2 = (const float*)d_in[40];
    float* out = (float*)d_out;

    // ---- workspace carve-up (M = 4*SP = 4352 rows) ----
    char* ws = (char*)d_ws;
    size_t off = 0;
    auto alc = [&](size_t b) { char* p = ws + off; off += (b + 255) & ~(size_t)255; return p; };
    float* h     = (float*)alc(4352L * 768 * 4);
    short* abuf  = (short*)alc(4352L * 768 * 2);
    short* gbuf  = (short*)alc(4352L * 3072 * 2);
    short* qb    = (short*)alc(4352L * 768 * 2);
    short* kb    = (short*)alc(4352L * 768 * 2);
    short* vt    = (short*)alc(48L * 64 * SP * 2);
    short* ctx   = (short*)alc(4352L * 768 * 2);
    short* fbuf  = (short*)alc(4352L * 768 * 2);
    short* vfbuf = (short*)alc(4352L * 768 * 2);
    short* hid   = (short*)alc(4352L * 384 * 2);
    short* wqkvT = (short*)alc(12L * 2304 * 768 * 2);
    short* woT   = (short*)alc(12L * 768 * 768 * 2);
    short* w1T   = (short*)alc(12L * 3072 * 768 * 2);
    short* w2T   = (short*)alc(12L * 768 * 3072 * 2);
    short* convT = (short*)alc(768L * 768 * 2);
    short* cqkvT = (short*)alc(2304L * 768 * 2);
    short* coT   = (short*)alc(768L * 768 * 2);
    short* fh1T  = (short*)alc(384L * 768 * 2);
    short* vh1T  = (short*)alc(384L * 768 * 2);
    short* ch1T  = (short*)alc(384L * 768 * 2);
    short* dummy = (short*)d_ws;

    // ---- weight prep (bf16 transposed [N,K]) ----
    wtrans<<<dim3(24, 24, 12), 256, 0, stream>>>(wq, 589824L, 768, 768, wqkvT, 1769472L, 0);
    wtrans<<<dim3(24, 24, 12), 256, 0, stream>>>(wk, 589824L, 768, 768, wqkvT, 1769472L, 768);
    wtrans<<<dim3(24, 24, 12), 256, 0, stream>>>(wv, 589824L, 768, 768, wqkvT, 1769472L, 1536);
    wtrans<<<dim3(24, 24, 12), 256, 0, stream>>>(wo, 589824L, 768, 768, woT, 589824L, 0);
    wtrans<<<dim3(24, 96, 12), 256, 0, stream>>>(w1, 2359296L, 768, 3072, w1T, 2359296L, 0);
    wtrans<<<dim3(96, 24, 12), 256, 0, stream>>>(w2, 2359296L, 3072, 768, w2T, 2359296L, 0);
    wtrans<<<dim3(24, 24, 1), 256, 0, stream>>>(cwq, 0, 768, 768, cqkvT, 0, 0);
    wtrans<<<dim3(24, 24, 1), 256, 0, stream>>>(cwk, 0, 768, 768, cqkvT, 0, 768);
    wtrans<<<dim3(24, 24, 1), 256, 0, stream>>>(cwv, 0, 768, 768, cqkvT, 0, 1536);
    wtrans<<<dim3(24, 24, 1), 256, 0, stream>>>(cwo, 0, 768, 768, coT, 0, 0);
    wtrans<<<dim3(24, 12, 1), 256, 0, stream>>>(fh_w1, 0, 768, 384, fh1T, 0, 0);
    wtrans<<<dim3(24, 12, 1), 256, 0, stream>>>(vh_w1, 0, 768, 384, vh1T, 0, 0);
    wtrans<<<dim3(24, 12, 1), 256, 0, stream>>>(ch_w1, 0, 768, 384, ch1T, 0, 0);
    f2b_k<<<2304, 256, 0, stream>>>(conv_w, convT, 589824L);

    // ---- patch embedding ----
    patch_gather<<<13056, 256, 0, stream>>>(x, abuf);
    gemm_bt<64, EPI_PATCH><<<dim3(34, 12), 256, 0, stream>>>(
        abuf, 768, convT, 768, 768,
        dummy, 768, conv_b, nullptr, nullptr, h, pos_emb, nullptr, nullptr);
    cls_fix<<<12, 256, 0, stream>>>(cls_tok, pos_emb, h);

    // ---- transformer blocks ----
    for (int l = 0; l < 12; l++) {
        ln_k<<<1088, 256, 0, stream>>>(h, ln1g + l * 768, ln1b + l * 768, abuf);
        gemm_bt<128, EPI_QKV><<<dim3(34, 18), 256, 0, stream>>>(
            abuf, 768, wqkvT + (long)l * 2304 * 768, 768, 768,
            qb, 768, bq + l * 768, bk + l * 768, bv + l * 768,
            nullptr, nullptr, kb, vt);
        flash_attn<<<dim3(17, 48), 256, 0, stream>>>(qb, kb, vt, ctx);
        gemm_bt<64, EPI_RES><<<dim3(34, 12), 256, 0, stream>>>(
            ctx, 768, woT + (long)l * 768 * 768, 768, 768,
            dummy, 768, bo + l * 768, nullptr, nullptr, h, nullptr, nullptr, nullptr);
        ln_k<<<1088, 256, 0, stream>>>(h, ln2g + l * 768, ln2b + l * 768, abuf);
        gemm_bt<128, EPI_GELU><<<dim3(34, 24), 256, 0, stream>>>(
            abuf, 768, w1T + (long)l * 3072 * 768, 768, 768,
            gbuf, 3072, b1 + l * 3072, nullptr, nullptr, nullptr, nullptr, nullptr, nullptr);
        if (l < 11) {
            gemm_bt<64, EPI_RES><<<dim3(34, 12), 256, 0, stream>>>(
                gbuf, 3072, w2T + (long)l * 768 * 3072, 3072, 3072,
                dummy, 768, b2 + l * 768, nullptr, nullptr, h, nullptr, nullptr, nullptr);
        } else {
            // final residual: also emit bf16 copy of h into fbuf
            gemm_bt<64, EPI_RESB><<<dim3(34, 12), 256, 0, stream>>>(
                gbuf, 3072, w2T + (long)l * 768 * 3072, 3072, 3072,
                fbuf, 768, b2 + l * 768, nullptr, nullptr, h, nullptr, nullptr, nullptr);
        }
    }

    // ---- cross-attention ----
    gemm_bt<128, EPI_QKV><<<dim3(34, 18), 256, 0, stream>>>(
        fbuf, 768, cqkvT, 768, 768,
        qb, 768, cbq, cbk, cbv, nullptr, nullptr, kb, vt);
    flash_attn<<<dim3(17, 48), 256, 0, stream>>>(qb, kb, vt, ctx);
    gemm_bt<64, EPI_BIAS><<<dim3(34, 12), 256, 0, stream>>>(
        ctx, 768, coT, 768, 768,
        vfbuf, 768, cbo, nullptr, nullptr, nullptr, nullptr, nullptr, nullptr);

    // ---- heads ----
    gemm_bt<64, EPI_GELU><<<dim3(34, 6), 256, 0, stream>>>(
        fbuf, 768, fh1T, 768, 768,
        hid, 384, fh_b1, nullptr, nullptr, nullptr, nullptr, nullptr, nullptr);
    logits_k<<<1025, 256, 0, stream>>>(hid, fh_w2, fh_b2, out + 0, 2);
    gemm_bt<64, EPI_GELU><<<dim3(34, 6), 256, 0, stream>>>(
        vfbuf, 768, vh1T, 768, 768,
        hid, 384, vh_b1, nullptr, nullptr, nullptr, nullptr, nullptr, nullptr);
    logits_k<<<1025, 256, 0, stream>>>(hid, vh_w2, vh_b2, out + 8200, 4);
    gemm_bt<64, EPI_GELU><<<dim3(34, 6), 256, 0, stream>>>(
        vfbuf, 768, ch1T, 768, 768,
        hid, 384, ch_b1, nullptr, nullptr, nullptr, nullptr, nullptr, nullptr);
    logits_k<<<1025, 256, 0, stream>>>(hid, ch_w2, ch_b2, out + 24600, 3);

    feats_out<<<3075, 256, 0, stream>>>(h, out + 36900);

    (void)in_sizes; (void)n_in; (void)out_size; (void)ws_size;
}